// Round 7
// baseline (668.345 us; speedup 1.0000x reference)
//
#include <hip/hip_runtime.h>
#include <math.h>

typedef short s16x8 __attribute__((ext_vector_type(8)));
typedef float f32x4 __attribute__((ext_vector_type(4)));
typedef unsigned u32x4 __attribute__((ext_vector_type(4)));
typedef unsigned short u16;

#define S_LEN 2048
#define HID_DIM 4096
#define NH_Q 32
#define NKV_H 8
#define DHEAD 128

__device__ __forceinline__ u16 f2bf(float f) {
  unsigned u = __builtin_bit_cast(unsigned, f);
  u += 0x7fffu + ((u >> 16) & 1u);
  return (u16)(u >> 16);
}

// async global -> LDS, 16B per lane; lds base wave-uniform, lane*16 auto-offset
__device__ __forceinline__ void gload16(const u16* g, u16* l) {
  __builtin_amdgcn_global_load_lds(
      (const __attribute__((address_space(1))) void*)g,
      (__attribute__((address_space(3))) void*)l, 16, 0, 0);
}

// ---------------- f32 -> bf16 bulk convert ----------------
__global__ void cvt_kernel(const float* __restrict__ in, u16* __restrict__ out, int n4) {
  int stride = gridDim.x * blockDim.x;
  for (int i = blockIdx.x * blockDim.x + threadIdx.x; i < n4; i += stride) {
    float4 f = ((const float4*)in)[i];
    uint2 o;
    o.x = (unsigned)f2bf(f.x) | ((unsigned)f2bf(f.y) << 16);
    o.y = (unsigned)f2bf(f.z) | ((unsigned)f2bf(f.w) << 16);
    ((uint2*)out)[i] = o;
  }
}

// ---------------- RoPE tables: cos/sin [S][64] ----------------
__global__ void rope_table_kernel(const int* __restrict__ positions,
                                  float* __restrict__ cos_t, float* __restrict__ sin_t) {
  int idx = blockIdx.x * 256 + threadIdx.x;
  if (idx >= S_LEN * 64) return;
  int s = idx >> 6, j = idx & 63;
  float pos = (float)positions[s];
  float inv = expf(-(float)j * (9.210340371976184f / 64.0f));
  float ang = pos * inv;
  float sv, cv;
  sincosf(ang, &sv, &cv);
  cos_t[idx] = cv;
  sin_t[idx] = sv;
}

// ---------------- 256^2-tile depth-2 pipelined GEMM: C = A[M][K]*B[N][K]^T ----
// BK=32, 8 waves (2Mx4N), TRIPLE-buffered LDS (96KB, 1 block/CU), gload_lds
// staging (linear dest, inverse-swizzled source), counted vmcnt(8) (depth-2
// prefetch, loads never drained to 0 mid-loop), 2 barriers/iter with ds_read
// and MFMA fused in one region (waves overlap LDS and MFMA pipes), T5 setprio.
// Wave (wr,wc): rows wr*128 + mf*16 (mf 0..7), cols wc*16 + (nf&1)*64 +
// (nf>>1)*128 (nf 0..3) == bn + wc*16 + nf*64 + l15 in epilogue order.
// EPI: 0 = f32 row-major out; 5 = fused QKV epilogue (outp = q base;
//      k = q+16777216, v = k+4194304; Q/K RoPE'd [b][h][s][d], V^T [b][h][d][s])
template<int EPI>
__global__ __launch_bounds__(512, 2) void gemmp2_kernel(
    const u16* __restrict__ A, const u16* __restrict__ B,
    void* __restrict__ outp, int M, int N, int K,
    const float* __restrict__ cos_t, const float* __restrict__ sin_t) {
  __shared__ u16 AsL[3][8192];  // [buf][2 chunks x 128 rows x 32], 16KB each
  __shared__ u16 BsL[3][8192];
  const int t = threadIdx.x;
  const int wave = t >> 6, lane = t & 63;
  const int l15 = lane & 15, lhi = lane >> 4;
  const int wr = wave >> 2, wc = wave & 3;
  // bijective XCD swizzle (grids are multiples of 8)
  const int gx = gridDim.x;
  const int nwg = gx * gridDim.y;
  const int id = blockIdx.y * gx + blockIdx.x;
  const int swz = (id & 7) * (nwg >> 3) + (id >> 3);
  const int bm = (swz / gx) * 256, bn = (swz % gx) * 256;

  // staging: thread t covers (row = t>>2 within 128-row chunk, phys slot = t&3);
  // source logical col = 8*((t&3) ^ ((t>>3)&3))  [inverse of read swizzle]
  const int srow = t >> 2;
  const int scol = 8 * ((t & 3) ^ ((t >> 3) & 3));
  const size_t ga0 = (size_t)(bm + srow) * K + scol;
  const size_t ga1 = (size_t)(bm + 128 + srow) * K + scol;
  const size_t gb0 = (size_t)(bn + srow) * K + scol;
  const size_t gb1 = (size_t)(bn + 128 + srow) * K + scol;
  const int ldst = wave * 512;  // + lane*16B implicit

  // read-side swizzled fragment offsets (elems): phys slot = lhi ^ ((l15>>1)&3)
  const int slotA = (lhi ^ ((l15 >> 1) & 3)) << 3;
  const int aidx = wr * 4096 + l15 * 32 + slotA;  // + mf*512
  int bidx[4];
#pragma unroll
  for (int nf = 0; nf < 4; ++nf)
    bidx[nf] = (nf >> 1) * 4096 + (wc * 16 + (nf & 1) * 64 + l15) * 32 + slotA;

  const f32x4 fz = {0.f, 0.f, 0.f, 0.f};
  f32x4 acc[8][4];
#pragma unroll
  for (int mf = 0; mf < 8; ++mf)
#pragma unroll
    for (int nf = 0; nf < 4; ++nf) acc[mf][nf] = fz;

  auto stage = [&](int tt, int buf) {
    const int kt = tt << 5;
    gload16(A + ga0 + kt, &AsL[buf][ldst]);
    gload16(A + ga1 + kt, &AsL[buf][4096 + ldst]);
    gload16(B + gb0 + kt, &BsL[buf][ldst]);
    gload16(B + gb1 + kt, &BsL[buf][4096 + ldst]);
  };

  const int nt = K >> 5;
  stage(0, 0);
  stage(1, 1);

  int cur = 0, nxt2 = 2;
  for (int tt = 0; tt < nt; ++tt) {
    // issue stage(t+2) into buf freed at iter t-1, then counted wait for tile t
    if (tt + 2 < nt) {
      stage(tt + 2, nxt2);
      asm volatile("s_waitcnt vmcnt(8)" ::: "memory");
    } else if (tt + 1 < nt) {
      asm volatile("s_waitcnt vmcnt(4)" ::: "memory");
    } else {
      asm volatile("s_waitcnt vmcnt(0)" ::: "memory");
    }
    __builtin_amdgcn_sched_barrier(0);
    __builtin_amdgcn_s_barrier();  // tile t visible to all waves
    __builtin_amdgcn_sched_barrier(0);

    const u16* Ab = &AsL[cur][0];
    const u16* Bb = &BsL[cur][0];
    s16x8 bf[4], af[4];
#pragma unroll
    for (int nf = 0; nf < 4; ++nf) bf[nf] = *(const s16x8*)&Bb[bidx[nf]];
#pragma unroll
    for (int mf = 0; mf < 4; ++mf) af[mf] = *(const s16x8*)&Ab[aidx + mf * 512];
    __builtin_amdgcn_s_setprio(1);
#pragma unroll
    for (int mf = 0; mf < 4; ++mf)
#pragma unroll
      for (int nf = 0; nf < 4; ++nf)
        acc[mf][nf] = __builtin_amdgcn_mfma_f32_16x16x32_bf16(af[mf], bf[nf], acc[mf][nf], 0, 0, 0);
    __builtin_amdgcn_s_setprio(0);
#pragma unroll
    for (int mf = 0; mf < 4; ++mf) af[mf] = *(const s16x8*)&Ab[aidx + (mf + 4) * 512];
    __builtin_amdgcn_s_setprio(1);
#pragma unroll
    for (int mf = 0; mf < 4; ++mf)
#pragma unroll
      for (int nf = 0; nf < 4; ++nf)
        acc[mf + 4][nf] =
            __builtin_amdgcn_mfma_f32_16x16x32_bf16(af[mf], bf[nf], acc[mf + 4][nf], 0, 0, 0);
    __builtin_amdgcn_s_setprio(0);

    asm volatile("s_waitcnt lgkmcnt(0)" ::: "memory");  // this wave's reads of buf cur done
    __builtin_amdgcn_sched_barrier(0);
    __builtin_amdgcn_s_barrier();  // all waves done reading buf cur -> free for stage(t+3)
    cur = (cur == 2) ? 0 : cur + 1;
    nxt2 = (nxt2 == 2) ? 0 : nxt2 + 1;
  }

  // ---- epilogue: row = bm + wr*128 + mf*16 + lhi*4 + i; col = bn + wc*16 + nf*64 + l15
  if (EPI == 0) {
    float* C = (float*)outp;
#pragma unroll
    for (int mf = 0; mf < 8; ++mf) {
      int rb = bm + wr * 128 + mf * 16 + lhi * 4;
#pragma unroll
      for (int nf = 0; nf < 4; ++nf) {
        int col = bn + wc * 16 + nf * 64 + l15;
#pragma unroll
        for (int i = 0; i < 4; ++i) C[(size_t)(rb + i) * N + col] = acc[mf][nf][i];
      }
    }
  } else {  // EPI == 5: fused QKV
    u16* qp = (u16*)outp;
    u16* kp = qp + 16777216;  // 2*32*2048*128
    u16* vp = kp + 4194304;   // 2*8*2048*128
    if (bn < 5120) {
      const bool isQ = bn < 4096;
      u16* O = isQ ? qp : kp;
      const int hb = isQ ? (bn >> 7) : ((bn - 4096) >> 7);
      const int Hh = isQ ? NH_Q : NKV_H;
      const int j = wc * 16 + l15;  // 0..63
#pragma unroll
      for (int mf = 0; mf < 8; ++mf) {
        int rb = bm + wr * 128 + mf * 16 + lhi * 4;
#pragma unroll
        for (int p = 0; p < 2; ++p) {
          int head = hb + p;
#pragma unroll
          for (int i = 0; i < 4; ++i) {
            int m = rb + i;
            int b = m >> 11, srw = m & 2047;
            float c = cos_t[srw * 64 + j];
            float s = sin_t[srw * 64 + j];
            float x0 = acc[mf][2 * p][i];
            float x1 = acc[mf][2 * p + 1][i];
            size_t base = ((size_t)(b * Hh + head) * S_LEN + srw) * DHEAD;
            O[base + j] = f2bf(x0 * c - x1 * s);
            O[base + j + 64] = f2bf(x0 * s + x1 * c);
          }
        }
      }
    } else {  // V transposed [b][h][d][s]
#pragma unroll
      for (int mf = 0; mf < 8; ++mf) {
        int rb = bm + wr * 128 + mf * 16 + lhi * 4;
#pragma unroll
        for (int nf = 0; nf < 4; ++nf) {
          int colrel = bn - 5120 + wc * 16 + nf * 64 + l15;
          int head = colrel >> 7, d = colrel & 127;
#pragma unroll
          for (int i = 0; i < 4; ++i) {
            int m = rb + i;
            int b = m >> 11, srw = m & 2047;
            vp[((size_t)(b * NKV_H + head) * DHEAD + d) * S_LEN + srw] = f2bf(acc[mf][nf][i]);
          }
        }
      }
    }
  }
}

// ---------------- reg-staged GEMM (fallback path only) ----------------
template<int EPI, bool ABF16, bool BBF16>
__global__ __launch_bounds__(256) void gemm_kernel(
    const void* __restrict__ Aptr, const void* __restrict__ Bptr,
    void* __restrict__ outp, void* __restrict__ outp2, int M, int N, int K,
    const float* __restrict__ cos_t, const float* __restrict__ sin_t, int Hh) {
  __shared__ u16 As[128][72];
  __shared__ u16 Bs[128][72];
  const int t = threadIdx.x;
  const int wave = t >> 6, lane = t & 63;
  const int l15 = lane & 15, lhi = lane >> 4;
  const int gx = gridDim.x;
  const int nwg = gx * gridDim.y;
  const int id = blockIdx.y * gx + blockIdx.x;
  const int swz = (id & 7) * (nwg >> 3) + (id >> 3);
  const int bm = (swz / gx) * 128, bn = (swz % gx) * 128;

  const f32x4 fz = {0.f, 0.f, 0.f, 0.f};
  f32x4 acc[2][8];
#pragma unroll
  for (int a0 = 0; a0 < 2; ++a0)
#pragma unroll
    for (int b0 = 0; b0 < 8; ++b0) acc[a0][b0] = fz;

  for (int kt = 0; kt < K; kt += 64) {
    __syncthreads();
    if (ABF16) {
      const u16* A = (const u16*)Aptr;
#pragma unroll
      for (int p = 0; p < 4; ++p) {
        int row = p * 32 + (t >> 3), kc = (t & 7) * 8;
        *(s16x8*)&As[row][kc] = *(const s16x8*)(A + (size_t)(bm + row) * K + kt + kc);
      }
    } else {
      const float* A = (const float*)Aptr;
#pragma unroll
      for (int p = 0; p < 8; ++p) {
        int row = p * 16 + (t >> 4), kc = (t & 15) * 4;
        float4 f = *(const float4*)(A + (size_t)(bm + row) * K + kt + kc);
        unsigned* dst = (unsigned*)&As[row][kc];
        dst[0] = (unsigned)f2bf(f.x) | ((unsigned)f2bf(f.y) << 16);
        dst[1] = (unsigned)f2bf(f.z) | ((unsigned)f2bf(f.w) << 16);
      }
    }
    if (BBF16) {
      const u16* Bw = (const u16*)Bptr;
#pragma unroll
      for (int p = 0; p < 4; ++p) {
        int row = p * 32 + (t >> 3), kc = (t & 7) * 8;
        *(s16x8*)&Bs[row][kc] = *(const s16x8*)(Bw + (size_t)(bn + row) * K + kt + kc);
      }
    } else {
      const float* Bw = (const float*)Bptr;
#pragma unroll
      for (int p = 0; p < 8; ++p) {
        int row = p * 16 + (t >> 4), kc = (t & 15) * 4;
        float4 f = *(const float4*)(Bw + (size_t)(bn + row) * K + kt + kc);
        unsigned* dst = (unsigned*)&Bs[row][kc];
        dst[0] = (unsigned)f2bf(f.x) | ((unsigned)f2bf(f.y) << 16);
        dst[1] = (unsigned)f2bf(f.z) | ((unsigned)f2bf(f.w) << 16);
      }
    }
    __syncthreads();
#pragma unroll
    for (int ks = 0; ks < 2; ++ks) {
      s16x8 bfr[8];
#pragma unroll
      for (int nf = 0; nf < 8; ++nf)
        bfr[nf] = *(const s16x8*)&Bs[nf * 16 + l15][ks * 32 + lhi * 8];
#pragma unroll
      for (int mf = 0; mf < 2; ++mf) {
        s16x8 a = *(const s16x8*)&As[wave * 32 + mf * 16 + l15][ks * 32 + lhi * 8];
#pragma unroll
        for (int nf = 0; nf < 8; ++nf)
          acc[mf][nf] = __builtin_amdgcn_mfma_f32_16x16x32_bf16(a, bfr[nf], acc[mf][nf], 0, 0, 0);
      }
    }
  }

  if (EPI == 0) {
    float* C = (float*)outp;
#pragma unroll
    for (int mf = 0; mf < 2; ++mf)
#pragma unroll
      for (int nf = 0; nf < 8; ++nf) {
        int col = bn + nf * 16 + l15;
        int rb = bm + wave * 32 + mf * 16 + lhi * 4;
#pragma unroll
        for (int i = 0; i < 4; ++i) C[(size_t)(rb + i) * N + col] = acc[mf][nf][i];
      }
  } else if (EPI == 2) {
    u16* O = (u16*)outp;
    int h = bn >> 7;
#pragma unroll
    for (int mf = 0; mf < 2; ++mf)
#pragma unroll
      for (int nf = 0; nf < 4; ++nf) {
        int j = nf * 16 + l15;
        int rb = bm + wave * 32 + mf * 16 + lhi * 4;
#pragma unroll
        for (int i = 0; i < 4; ++i) {
          int m = rb + i;
          int b = m >> 11, srow = m & 2047;
          float c = cos_t[srow * 64 + j];
          float s = sin_t[srow * 64 + j];
          float x0 = acc[mf][nf][i];
          float x1 = acc[mf][nf + 4][i];
          size_t base = ((size_t)(b * Hh + h) * S_LEN + srow) * DHEAD;
          O[base + j] = f2bf(x0 * c - x1 * s);
          O[base + j + 64] = f2bf(x0 * s + x1 * c);
        }
      }
  } else {  // EPI == 4: bf16 transposed [b][h][d][s]
    u16* O = (u16*)outp;
#pragma unroll
    for (int mf = 0; mf < 2; ++mf)
#pragma unroll
      for (int nf = 0; nf < 8; ++nf) {
        int col = bn + nf * 16 + l15;
        int h = col >> 7, d = col & 127;
        int rb = bm + wave * 32 + mf * 16 + lhi * 4;
#pragma unroll
        for (int i = 0; i < 4; ++i) {
          int m = rb + i;
          int b = m >> 11, srow = m & 2047;
          O[((size_t)(b * Hh + h) * DHEAD + d) * S_LEN + srow] = f2bf(acc[mf][nf][i]);
        }
      }
  }
}

// ---------------- Flash attention (causal, GQA) ----------------
#define KIDX(r, c) (((r) * 128 + (c)) ^ (((r) & 7) << 3))
#define VIDX(d, kv) (((d) * 64 + (kv)) ^ (((d) & 7) << 3))
__global__ __launch_bounds__(512) void attn_kernel(
    const u16* __restrict__ q, const u16* __restrict__ k, const u16* __restrict__ vt,
    u16* __restrict__ ctx) {
  __shared__ u16 Ks[64 * 128];
  __shared__ u16 Vts[128 * 64];

  const int t = threadIdx.x;
  const int wave = t >> 6, lane = t & 63;
  const int l15 = lane & 15, lhi = lane >> 4;
  const int pi = blockIdx.x, h = blockIdx.y, b = blockIdx.z;
  const int kvh = h >> 2;
  const int qsub[2] = {pi, 15 - pi};
  const int ntiles = 32 - 2 * pi;

  const u16* qb = q + ((size_t)(b * NH_Q + h)) * S_LEN * DHEAD;
  const u16* kb = k + ((size_t)(b * NKV_H + kvh)) * S_LEN * DHEAD;
  const u16* vtb = vt + ((size_t)(b * NKV_H + kvh)) * DHEAD * S_LEN;

  s16x8 qf[2][4];
#pragma unroll
  for (int s = 0; s < 2; ++s)
#pragma unroll
    for (int ks = 0; ks < 4; ++ks)
      qf[s][ks] = *(const s16x8*)(qb + (size_t)(qsub[s] * 128 + wave * 16 + l15) * DHEAD +
                                  ks * 32 + lhi * 8);

  const f32x4 fz = {0.f, 0.f, 0.f, 0.f};
  f32x4 acc[2][8];
#pragma unroll
  for (int s = 0; s < 2; ++s)
#pragma unroll
    for (int i = 0; i < 8; ++i) acc[s][i] = fz;
  float mrow[2] = {-INFINITY, -INFINITY};
  float lsum[2] = {0.f, 0.f};

  const float scale = 0.08838834764831845f;

  const int sl0 = l15 | (((2 * lhi) & 3) << 4);
  const int sl1 = sl0 | 16;
  const bool hisel = (lhi & 2) != 0;

  const int krow = t >> 3, kd0 = (t & 7) * 16;
  const int vrow = t >> 2, vk0 = (t & 3) * 16;
  s16x8 kr0, kr1, vr0, vr1;
  {
    const u16* p = kb + (size_t)krow * DHEAD + kd0;
    kr0 = *(const s16x8*)p;
    kr1 = *(const s16x8*)(p + 8);
    const u16* pv = vtb + (size_t)vrow * S_LEN + vk0;
    vr0 = *(const s16x8*)pv;
    vr1 = *(const s16x8*)(pv + 8);
  }

  for (int tt = 0; tt < ntiles; ++tt) {
    __syncthreads();
    *(s16x8*)&Ks[KIDX(krow, kd0)] = kr0;
    *(s16x8*)&Ks[KIDX(krow, kd0 + 8)] = kr1;
    *(s16x8*)&Vts[VIDX(vrow, vk0)] = vr0;
    *(s16x8*)&Vts[VIDX(vrow, vk0 + 8)] = vr1;
    __syncthreads();
    if (tt + 1 < ntiles) {
      const u16* p = kb + (size_t)((tt + 1) * 64 + krow) * DHEAD + kd0;
      kr0 = *(const s16x8*)p;
      kr1 = *(const s16x8*)(p + 8);
      const u16* pv = vtb + (size_t)vrow * S_LEN + (tt + 1) * 64 + vk0;
      vr0 = *(const s16x8*)pv;
      vr1 = *(const s16x8*)(pv + 8);
    }

    const int kc_base = tt * 64;
#pragma unroll
    for (int s = 0; s < 2; ++s) {
      const int wmin = qsub[s] * 128 + wave * 16;
      if (kc_base > wmin + 15) continue;
      f32x4 sacc[4];
#pragma unroll
      for (int i = 0; i < 4; ++i) sacc[i] = fz;
      __builtin_amdgcn_s_setprio(1);
#pragma unroll
      for (int ks = 0; ks < 4; ++ks) {
#pragma unroll
        for (int nf = 0; nf < 4; ++nf) {
          s16x8 kf = *(const s16x8*)&Ks[KIDX(nf * 16 + l15, ks * 32 + lhi * 8)];
          sacc[nf] = __builtin_amdgcn_mfma_f32_16x16x32_bf16(kf, qf[s][ks], sacc[nf], 0, 0, 0);
        }
      }
      __builtin_amdgcn_s_setprio(0);

      const int qg = wmin + l15;
      float pmax = -INFINITY;
      if (kc_base + 63 > wmin) {
#pragma unroll
        for (int nf = 0; nf < 4; ++nf)
#pragma unroll
          for (int i = 0; i < 4; ++i) {
            int kv = kc_base + nf * 16 + lhi * 4 + i;
            float sv = sacc[nf][i] * scale;
            sv = (kv <= qg) ? sv : -INFINITY;
            sacc[nf][i] = sv;
            pmax = fmaxf(pmax, sv);
          }
      } else {
#pragma unroll
        for (int nf = 0; nf < 4; ++nf)
#pragma unroll
          for (int i = 0; i < 4; ++i) {
            float sv = sacc[nf][i] * scale;
            sacc[nf][i] = sv;
            pmax = fmaxf(pmax, sv);
          }
      }
      pmax = fmaxf(pmax, __shfl_xor(pmax, 16, 64));
      pmax = fmaxf(pmax, __shfl_xor(pmax, 32, 64));

      if (!__all(pmax <= mrow[s] + 8.0f)) {
        float mnew = fmaxf(mrow[s], pmax);
        float alpha = __expf(mrow[s] - mnew);
        mrow[s] = mnew;
        lsum[s] *= alpha;
#pragma unroll
        for (int i = 0; i < 4; ++i) {
          float al = __shfl(alpha, (lane & 48) | (lhi * 4 + i), 64);
#pragma unroll
          for (int df = 0; df < 8; ++df) acc[s][df][i] *= al;
        }
      }

      float rsum = 0.f;
      unsigned pk[4][2];
#pragma unroll
      for (int nf = 0; nf < 4; ++nf) {
        float p0 = __expf(sacc[nf][0] - mrow[s]);
        float p1 = __expf(sacc[nf][1] - mrow[s]);
        float p2 = __expf(sacc[nf][2] - mrow[s]);
        float p3 = __expf(sacc[nf][3] - mrow[s]);
        rsum += (p0 + p1) + (p2 + p3);
        pk[nf][0] = (unsigned)f2bf(p0) | ((unsigned)f2bf(p1) << 16);
        pk[nf][1] = (unsigned)f2bf(p2) | ((unsigned)f2bf(p3) << 16);
      }
      rsum += __shfl_xor(rsum, 16, 64);
      rsum += __shfl_xor(rsum, 32, 64);
      lsum[s] += rsum;

      s16x8 pa[2];
#pragma unroll
      for (int ph = 0; ph < 2; ++ph) {
        unsigned lo0 = __shfl((int)pk[2 * ph][0], sl0, 64);
        unsigned hi0 = __shfl((int)pk[2 * ph + 1][0], sl0, 64);
        unsigned lo1 = __shfl((int)pk[2 * ph][1], sl0, 64);
        unsigned hi1 = __shfl((int)pk[2 * ph + 1][1], sl0, 64);
        unsigned lo2 = __shfl((int)pk[2 * ph][0], sl1, 64);
        unsigned hi2 = __shfl((int)pk[2 * ph + 1][0], sl1, 64);
        unsigned lo3 = __shfl((int)pk[2 * ph][1], sl1, 64);
        unsigned hi3 = __shfl((int)pk[2 * ph + 1][1], sl1, 64);
        u32x4 w;
        w[0] = hisel ? hi0 : lo0;
        w[1] = hisel ? hi1 : lo1;
        w[2] = hisel ? hi2 : lo2;
        w[3] = hisel ? hi3 : lo3;
        pa[ph] = __builtin_bit_cast(s16x8, w);
      }

      __builtin_amdgcn_s_setprio(1);
#pragma unroll
      for (int ph = 0; ph < 2; ++ph) {
#pragma unroll
        for (int df = 0; df < 8; ++df) {
          s16x8 bb = *(const s16x8*)&Vts[VIDX(df * 16 + l15, ph * 32 + lhi * 8)];
          acc[s][df] = __builtin_amdgcn_mfma_f32_16x16x32_bf16(pa[ph], bb, acc[s][df], 0, 0, 0);
        }
      }
      __builtin_amdgcn_s_setprio(0);
    }
  }

#pragma unroll
  for (int s = 0; s < 2; ++s) {
    float rl = 1.0f / lsum[s];
#pragma unroll
    for (int i = 0; i < 4; ++i) {
      float rli = __shfl(rl, (lane & 48) | (lhi * 4 + i), 64);
      int m = b * S_LEN + qsub[s] * 128 + wave * 16 + lhi * 4 + i;
#pragma unroll
      for (int df = 0; df < 8; ++df) {
        int col = h * DHEAD + df * 16 + l15;
        ctx[(size_t)m * (NH_Q * DHEAD) + col] = f2bf(acc[s][df][i] * rli);
      }
    }
  }
}

extern "C" void kernel_launch(void* const* d_in, const int* in_sizes, int n_in,
                              void* d_out, int out_size, void* d_ws, size_t ws_size,
                              hipStream_t stream) {
  const float* x = (const float*)d_in[0];
  const int* positions = (const int*)d_in[1];
  const float* wq = (const float*)d_in[2];
  const float* wk = (const float*)d_in[3];
  const float* wv = (const float*)d_in[4];
  const float* wo = (const float*)d_in[5];
  float* out = (float*)d_out;

  char* ws = (char*)d_ws;
  const size_t MB1 = 1048576;
  const size_t SZ_X = 33554432;     // 2*2048*4096 bf16
  const size_t SZ_WQKV = 50331648;  // 6144*4096 bf16
  const size_t SZ_Q = 33554432;     // q bf16
  const size_t SZ_WK = 8388608;     // k or v bf16
  const size_t NEED_FULL = MB1 + SZ_X + SZ_WQKV + SZ_Q + 2 * SZ_WK;  // 129 MB

  float* cos_t = (float*)ws;
  float* sin_t = (float*)(ws + MB1 / 2);

  rope_table_kernel<<<512, 256, 0, stream>>>(positions, cos_t, sin_t);

  if (ws_size >= NEED_FULL) {
    char* p = ws + MB1;
    u16* x_bf = (u16*)p;    p += SZ_X;     // later reused as ctx
    u16* wqkv_bf = (u16*)p; p += SZ_WQKV;  // wq|wk|wv stacked; wo after QKV gemm
    u16* q_ws = (u16*)p;    p += SZ_Q;     // q | k | v contiguous
    u16* k_ws = (u16*)p;    p += SZ_WK;
    u16* v_ws = (u16*)p;    p += SZ_WK;
    u16* ctx_ws = x_bf;

    cvt_kernel<<<2048, 256, 0, stream>>>(x, x_bf, 4194304);
    cvt_kernel<<<2048, 256, 0, stream>>>(wq, wqkv_bf, 4194304);
    cvt_kernel<<<1024, 256, 0, stream>>>(wk, wqkv_bf + 16777216, 1048576);
    cvt_kernel<<<1024, 256, 0, stream>>>(wv, wqkv_bf + 20971520, 1048576);

    // fused QKV: N = 6144 (cols 0-4095 Q, 4096-5119 K, 5120-6143 V)
    gemmp2_kernel<5><<<dim3(24, 16), 512, 0, stream>>>(
        x_bf, wqkv_bf, q_ws, 4096, 6144, 4096, cos_t, sin_t);
    cvt_kernel<<<2048, 256, 0, stream>>>(wo, wqkv_bf, 4194304);  // wqkv_bf now = wo_bf
    attn_kernel<<<dim3(8, 32, 2), 512, 0, stream>>>(q_ws, k_ws, v_ws, ctx_ws);
    gemmp2_kernel<0><<<dim3(16, 16), 512, 0, stream>>>(
        ctx_ws, wqkv_bf, out, 4096, 4096, 4096, nullptr, nullptr);
  } else {
    u16* q_ws = (u16*)(ws + MB1);
    u16* k_ws = (u16*)(ws + MB1 + SZ_Q);
    u16* v_ws = (u16*)(ws + MB1 + SZ_Q + SZ_WK);
    u16* ctx_ws = (u16*)(ws + MB1 + SZ_Q + 2 * SZ_WK);

    gemm_kernel<2, false, false><<<dim3(32, 32), 256, 0, stream>>>(
        x, wq, q_ws, nullptr, 4096, 4096, 4096, cos_t, sin_t, NH_Q);
    gemm_kernel<2, false, false><<<dim3(8, 32), 256, 0, stream>>>(
        x, wk, k_ws, nullptr, 4096, 1024, 4096, cos_t, sin_t, NKV_H);
    gemm_kernel<4, false, false><<<dim3(8, 32), 256, 0, stream>>>(
        x, wv, v_ws, nullptr, 4096, 1024, 4096, nullptr, nullptr, NKV_H);
    attn_kernel<<<dim3(8, 32, 2), 512, 0, stream>>>(q_ws, k_ws, v_ws, ctx_ws);
    gemm_kernel<0, true, false><<<dim3(32, 32), 256, 0, stream>>>(
        ctx_ws, wo, out, nullptr, 4096, 4096, 4096, nullptr, nullptr, 0);
  }
}

// Round 8
// 644.543 us; speedup vs baseline: 1.0369x; 1.0369x over previous
//
#include <hip/hip_runtime.h>
#include <math.h>

typedef short s16x8 __attribute__((ext_vector_type(8)));
typedef float f32x4 __attribute__((ext_vector_type(4)));
typedef unsigned u32x4 __attribute__((ext_vector_type(4)));
typedef unsigned short u16;

#define S_LEN 2048
#define HID_DIM 4096
#define NH_Q 32
#define NKV_H 8
#define DHEAD 128

__device__ __forceinline__ u16 f2bf(float f) {
  unsigned u = __builtin_bit_cast(unsigned, f);
  u += 0x7fffu + ((u >> 16) & 1u);
  return (u16)(u >> 16);
}

// async global -> LDS, 16B per lane; lds base wave-uniform, lane*16 auto-offset
__device__ __forceinline__ void gload16(const u16* g, u16* l) {
  __builtin_amdgcn_global_load_lds(
      (const __attribute__((address_space(1))) void*)g,
      (__attribute__((address_space(3))) void*)l, 16, 0, 0);
}

// ---------------- f32 -> bf16 bulk convert ----------------
__global__ void cvt_kernel(const float* __restrict__ in, u16* __restrict__ out, int n4) {
  int stride = gridDim.x * blockDim.x;
  for (int i = blockIdx.x * blockDim.x + threadIdx.x; i < n4; i += stride) {
    float4 f = ((const float4*)in)[i];
    uint2 o;
    o.x = (unsigned)f2bf(f.x) | ((unsigned)f2bf(f.y) << 16);
    o.y = (unsigned)f2bf(f.z) | ((unsigned)f2bf(f.w) << 16);
    ((uint2*)out)[i] = o;
  }
}

// ---------------- RoPE tables: cos/sin [S][64] ----------------
__global__ void rope_table_kernel(const int* __restrict__ positions,
                                  float* __restrict__ cos_t, float* __restrict__ sin_t) {
  int idx = blockIdx.x * 256 + threadIdx.x;
  if (idx >= S_LEN * 64) return;
  int s = idx >> 6, j = idx & 63;
  float pos = (float)positions[s];
  float inv = expf(-(float)j * (9.210340371976184f / 64.0f));
  float ang = pos * inv;
  float sv, cv;
  sincosf(ang, &sv, &cv);
  cos_t[idx] = cv;
  sin_t[idx] = sv;
}

// ---------------- double-buffered pipelined GEMM: C = A[M][K]*B[N][K]^T ----
// Tile: (MF*32) x 256, BK=32, 8 waves (2M x 4N). MF=8 -> 256x256, 64KB LDS
// (2 blocks/CU); MF=4 -> 128x256, 48KB LDS (3 blocks/CU).
// gload_lds staging (linear dest, inverse-swizzled source), counted vmcnt
// (next tile stays in flight across compute), exactly 2 barriers/iter,
// reads+MFMA in one region (compiler interleaves via fine lgkmcnt), T5 setprio.
// Wave (wr,wc): rows wr*(MF*16) + mf*16, cols wc*16 + nf*64 (RoPE pairs in-wave).
// EPI: 0 = f32 row-major out; 5 = fused QKV epilogue (MF=8 only; outp = q base,
//      k = q+16777216, v = k+4194304; Q/K RoPE'd [b][h][s][d], V^T [b][h][d][s])
template<int EPI, int MF>
__global__ __launch_bounds__(512, 2) void gemmdb_kernel(
    const u16* __restrict__ A, const u16* __restrict__ B,
    void* __restrict__ outp, int M, int N, int K,
    const float* __restrict__ cos_t, const float* __restrict__ sin_t) {
  constexpr int ACH = MF / 4;  // A 128-row chunks
  __shared__ u16 AsL[2][ACH * 4096];
  __shared__ u16 BsL[2][8192];
  const int t = threadIdx.x;
  const int wave = t >> 6, lane = t & 63;
  const int l15 = lane & 15, lhi = lane >> 4;
  const int wr = wave >> 2, wc = wave & 3;
  // bijective XCD swizzle (grids are multiples of 8)
  const int gx = gridDim.x;
  const int nwg = gx * gridDim.y;
  const int id = blockIdx.y * gx + blockIdx.x;
  const int swz = (id & 7) * (nwg >> 3) + (id >> 3);
  const int bm = (swz / gx) * (MF * 32), bn = (swz % gx) * 256;

  // staging: thread t covers (row = t>>2 within 128-row chunk, phys slot = t&3);
  // source logical col = 8*((t&3) ^ ((t>>3)&3))  [inverse of read swizzle]
  const int srow = t >> 2;
  const int scol = 8 * ((t & 3) ^ ((t >> 3) & 3));
  const size_t ga0 = (size_t)(bm + srow) * K + scol;
  const size_t ga1 = (size_t)(bm + 128 + srow) * K + scol;  // MF==8 only
  const size_t gb0 = (size_t)(bn + srow) * K + scol;
  const size_t gb1 = (size_t)(bn + 128 + srow) * K + scol;
  const int ldst = wave * 512;  // + lane*16B implicit

  // read-side swizzled fragment offsets (elems): phys slot = lhi ^ ((l15>>1)&3)
  const int slotA = (lhi ^ ((l15 >> 1) & 3)) << 3;
  const int aidx = wr * (ACH == 2 ? 4096 : 2048) + l15 * 32 + slotA;  // + mf*512
  int bidx[4];
#pragma unroll
  for (int nf = 0; nf < 4; ++nf)
    bidx[nf] = (nf >> 1) * 4096 + (wc * 16 + (nf & 1) * 64 + l15) * 32 + slotA;

  const f32x4 fz = {0.f, 0.f, 0.f, 0.f};
  f32x4 acc[MF][4];
#pragma unroll
  for (int mf = 0; mf < MF; ++mf)
#pragma unroll
    for (int nf = 0; nf < 4; ++nf) acc[mf][nf] = fz;

  auto stage = [&](int tt, int buf) {
    const int kt = tt << 5;
    gload16(A + ga0 + kt, &AsL[buf][ldst]);
    if constexpr (MF == 8) gload16(A + ga1 + kt, &AsL[buf][4096 + ldst]);
    gload16(B + gb0 + kt, &BsL[buf][ldst]);
    gload16(B + gb1 + kt, &BsL[buf][4096 + ldst]);
  };

  const int nt = K >> 5;
  stage(0, 0);

  for (int tt = 0; tt < nt; ++tt) {
    const int cur = tt & 1;
    // issue next tile into the other buffer (freed at end of iter tt-1),
    // then counted wait: only tile tt's loads must be complete.
    if (tt + 1 < nt) {
      stage(tt + 1, cur ^ 1);
      if constexpr (MF == 8)
        asm volatile("s_waitcnt vmcnt(4)" ::: "memory");
      else
        asm volatile("s_waitcnt vmcnt(3)" ::: "memory");
    } else {
      asm volatile("s_waitcnt vmcnt(0)" ::: "memory");
    }
    __builtin_amdgcn_sched_barrier(0);
    __builtin_amdgcn_s_barrier();  // tile tt visible to all waves
    __builtin_amdgcn_sched_barrier(0);

    const u16* Ab = &AsL[cur][0];
    const u16* Bb = &BsL[cur][0];
    s16x8 bf[4], af[MF];
#pragma unroll
    for (int nf = 0; nf < 4; ++nf) bf[nf] = *(const s16x8*)&Bb[bidx[nf]];
#pragma unroll
    for (int mf = 0; mf < MF; ++mf) af[mf] = *(const s16x8*)&Ab[aidx + mf * 512];
    __builtin_amdgcn_s_setprio(1);
#pragma unroll
    for (int mf = 0; mf < MF; ++mf)
#pragma unroll
      for (int nf = 0; nf < 4; ++nf)
        acc[mf][nf] = __builtin_amdgcn_mfma_f32_16x16x32_bf16(af[mf], bf[nf], acc[mf][nf], 0, 0, 0);
    __builtin_amdgcn_s_setprio(0);

    asm volatile("s_waitcnt lgkmcnt(0)" ::: "memory");  // wave's reads of buf cur done
    __builtin_amdgcn_sched_barrier(0);
    __builtin_amdgcn_s_barrier();  // all waves done reading cur -> stage may reuse it
  }

  // ---- epilogue: row = bm + wr*(MF*16) + mf*16 + lhi*4 + i; col = bn + wc*16 + nf*64 + l15
  if constexpr (EPI == 0) {
    float* C = (float*)outp;
#pragma unroll
    for (int mf = 0; mf < MF; ++mf) {
      int rb = bm + wr * (MF * 16) + mf * 16 + lhi * 4;
#pragma unroll
      for (int nf = 0; nf < 4; ++nf) {
        int col = bn + wc * 16 + nf * 64 + l15;
#pragma unroll
        for (int i = 0; i < 4; ++i) C[(size_t)(rb + i) * N + col] = acc[mf][nf][i];
      }
    }
  } else {  // EPI == 5: fused QKV (MF == 8)
    u16* qp = (u16*)outp;
    u16* kp = qp + 16777216;  // 2*32*2048*128
    u16* vp = kp + 4194304;   // 2*8*2048*128
    if (bn < 5120) {
      const bool isQ = bn < 4096;
      u16* O = isQ ? qp : kp;
      const int hb = isQ ? (bn >> 7) : ((bn - 4096) >> 7);
      const int Hh = isQ ? NH_Q : NKV_H;
      const int j = wc * 16 + l15;  // 0..63
#pragma unroll
      for (int mf = 0; mf < MF; ++mf) {
        int rb = bm + wr * (MF * 16) + mf * 16 + lhi * 4;
#pragma unroll
        for (int p = 0; p < 2; ++p) {
          int head = hb + p;
#pragma unroll
          for (int i = 0; i < 4; ++i) {
            int m = rb + i;
            int b = m >> 11, srw = m & 2047;
            float c = cos_t[srw * 64 + j];
            float s = sin_t[srw * 64 + j];
            float x0 = acc[mf][2 * p][i];
            float x1 = acc[mf][2 * p + 1][i];
            size_t base = ((size_t)(b * Hh + head) * S_LEN + srw) * DHEAD;
            O[base + j] = f2bf(x0 * c - x1 * s);
            O[base + j + 64] = f2bf(x0 * s + x1 * c);
          }
        }
      }
    } else {  // V transposed [b][h][d][s]
#pragma unroll
      for (int mf = 0; mf < MF; ++mf) {
        int rb = bm + wr * (MF * 16) + mf * 16 + lhi * 4;
#pragma unroll
        for (int nf = 0; nf < 4; ++nf) {
          int colrel = bn - 5120 + wc * 16 + nf * 64 + l15;
          int head = colrel >> 7, d = colrel & 127;
#pragma unroll
          for (int i = 0; i < 4; ++i) {
            int m = rb + i;
            int b = m >> 11, srw = m & 2047;
            vp[((size_t)(b * NKV_H + head) * DHEAD + d) * S_LEN + srw] = f2bf(acc[mf][nf][i]);
          }
        }
      }
    }
  }
}

// ---------------- reg-staged GEMM (fallback path only) ----------------
template<int EPI, bool ABF16, bool BBF16>
__global__ __launch_bounds__(256) void gemm_kernel(
    const void* __restrict__ Aptr, const void* __restrict__ Bptr,
    void* __restrict__ outp, void* __restrict__ outp2, int M, int N, int K,
    const float* __restrict__ cos_t, const float* __restrict__ sin_t, int Hh) {
  __shared__ u16 As[128][72];
  __shared__ u16 Bs[128][72];
  const int t = threadIdx.x;
  const int wave = t >> 6, lane = t & 63;
  const int l15 = lane & 15, lhi = lane >> 4;
  const int gx = gridDim.x;
  const int nwg = gx * gridDim.y;
  const int id = blockIdx.y * gx + blockIdx.x;
  const int swz = (id & 7) * (nwg >> 3) + (id >> 3);
  const int bm = (swz / gx) * 128, bn = (swz % gx) * 128;

  const f32x4 fz = {0.f, 0.f, 0.f, 0.f};
  f32x4 acc[2][8];
#pragma unroll
  for (int a0 = 0; a0 < 2; ++a0)
#pragma unroll
    for (int b0 = 0; b0 < 8; ++b0) acc[a0][b0] = fz;

  for (int kt = 0; kt < K; kt += 64) {
    __syncthreads();
    if (ABF16) {
      const u16* A = (const u16*)Aptr;
#pragma unroll
      for (int p = 0; p < 4; ++p) {
        int row = p * 32 + (t >> 3), kc = (t & 7) * 8;
        *(s16x8*)&As[row][kc] = *(const s16x8*)(A + (size_t)(bm + row) * K + kt + kc);
      }
    } else {
      const float* A = (const float*)Aptr;
#pragma unroll
      for (int p = 0; p < 8; ++p) {
        int row = p * 16 + (t >> 4), kc = (t & 15) * 4;
        float4 f = *(const float4*)(A + (size_t)(bm + row) * K + kt + kc);
        unsigned* dst = (unsigned*)&As[row][kc];
        dst[0] = (unsigned)f2bf(f.x) | ((unsigned)f2bf(f.y) << 16);
        dst[1] = (unsigned)f2bf(f.z) | ((unsigned)f2bf(f.w) << 16);
      }
    }
    if (BBF16) {
      const u16* Bw = (const u16*)Bptr;
#pragma unroll
      for (int p = 0; p < 4; ++p) {
        int row = p * 32 + (t >> 3), kc = (t & 7) * 8;
        *(s16x8*)&Bs[row][kc] = *(const s16x8*)(Bw + (size_t)(bn + row) * K + kt + kc);
      }
    } else {
      const float* Bw = (const float*)Bptr;
#pragma unroll
      for (int p = 0; p < 8; ++p) {
        int row = p * 16 + (t >> 4), kc = (t & 15) * 4;
        float4 f = *(const float4*)(Bw + (size_t)(bn + row) * K + kt + kc);
        unsigned* dst = (unsigned*)&Bs[row][kc];
        dst[0] = (unsigned)f2bf(f.x) | ((unsigned)f2bf(f.y) << 16);
        dst[1] = (unsigned)f2bf(f.z) | ((unsigned)f2bf(f.w) << 16);
      }
    }
    __syncthreads();
#pragma unroll
    for (int ks = 0; ks < 2; ++ks) {
      s16x8 bfr[8];
#pragma unroll
      for (int nf = 0; nf < 8; ++nf)
        bfr[nf] = *(const s16x8*)&Bs[nf * 16 + l15][ks * 32 + lhi * 8];
#pragma unroll
      for (int mf = 0; mf < 2; ++mf) {
        s16x8 a = *(const s16x8*)&As[wave * 32 + mf * 16 + l15][ks * 32 + lhi * 8];
#pragma unroll
        for (int nf = 0; nf < 8; ++nf)
          acc[mf][nf] = __builtin_amdgcn_mfma_f32_16x16x32_bf16(a, bfr[nf], acc[mf][nf], 0, 0, 0);
      }
    }
  }

  if (EPI == 0) {
    float* C = (float*)outp;
#pragma unroll
    for (int mf = 0; mf < 2; ++mf)
#pragma unroll
      for (int nf = 0; nf < 8; ++nf) {
        int col = bn + nf * 16 + l15;
        int rb = bm + wave * 32 + mf * 16 + lhi * 4;
#pragma unroll
        for (int i = 0; i < 4; ++i) C[(size_t)(rb + i) * N + col] = acc[mf][nf][i];
      }
  } else if (EPI == 2) {
    u16* O = (u16*)outp;
    int h = bn >> 7;
#pragma unroll
    for (int mf = 0; mf < 2; ++mf)
#pragma unroll
      for (int nf = 0; nf < 4; ++nf) {
        int j = nf * 16 + l15;
        int rb = bm + wave * 32 + mf * 16 + lhi * 4;
#pragma unroll
        for (int i = 0; i < 4; ++i) {
          int m = rb + i;
          int b = m >> 11, srow = m & 2047;
          float c = cos_t[srow * 64 + j];
          float s = sin_t[srow * 64 + j];
          float x0 = acc[mf][nf][i];
          float x1 = acc[mf][nf + 4][i];
          size_t base = ((size_t)(b * Hh + h) * S_LEN + srow) * DHEAD;
          O[base + j] = f2bf(x0 * c - x1 * s);
          O[base + j + 64] = f2bf(x0 * s + x1 * c);
        }
      }
  } else {  // EPI == 4: bf16 transposed [b][h][d][s]
    u16* O = (u16*)outp;
#pragma unroll
    for (int mf = 0; mf < 2; ++mf)
#pragma unroll
      for (int nf = 0; nf < 8; ++nf) {
        int col = bn + nf * 16 + l15;
        int h = col >> 7, d = col & 127;
        int rb = bm + wave * 32 + mf * 16 + lhi * 4;
#pragma unroll
        for (int i = 0; i < 4; ++i) {
          int m = rb + i;
          int b = m >> 11, srow = m & 2047;
          O[((size_t)(b * Hh + h) * DHEAD + d) * S_LEN + srow] = f2bf(acc[mf][nf][i]);
        }
      }
  }
}

// ---------------- Flash attention (causal, GQA) ----------------
#define KIDX(r, c) (((r) * 128 + (c)) ^ (((r) & 7) << 3))
#define VIDX(d, kv) (((d) * 64 + (kv)) ^ (((d) & 7) << 3))
__global__ __launch_bounds__(512) void attn_kernel(
    const u16* __restrict__ q, const u16* __restrict__ k, const u16* __restrict__ vt,
    u16* __restrict__ ctx) {
  __shared__ u16 Ks[64 * 128];
  __shared__ u16 Vts[128 * 64];

  const int t = threadIdx.x;
  const int wave = t >> 6, lane = t & 63;
  const int l15 = lane & 15, lhi = lane >> 4;
  const int pi = blockIdx.x, h = blockIdx.y, b = blockIdx.z;
  const int kvh = h >> 2;
  const int qsub[2] = {pi, 15 - pi};
  const int ntiles = 32 - 2 * pi;

  const u16* qb = q + ((size_t)(b * NH_Q + h)) * S_LEN * DHEAD;
  const u16* kb = k + ((size_t)(b * NKV_H + kvh)) * S_LEN * DHEAD;
  const u16* vtb = vt + ((size_t)(b * NKV_H + kvh)) * DHEAD * S_LEN;

  s16x8 qf[2][4];
#pragma unroll
  for (int s = 0; s < 2; ++s)
#pragma unroll
    for (int ks = 0; ks < 4; ++ks)
      qf[s][ks] = *(const s16x8*)(qb + (size_t)(qsub[s] * 128 + wave * 16 + l15) * DHEAD +
                                  ks * 32 + lhi * 8);

  const f32x4 fz = {0.f, 0.f, 0.f, 0.f};
  f32x4 acc[2][8];
#pragma unroll
  for (int s = 0; s < 2; ++s)
#pragma unroll
    for (int i = 0; i < 8; ++i) acc[s][i] = fz;
  float mrow[2] = {-INFINITY, -INFINITY};
  float lsum[2] = {0.f, 0.f};

  const float scale = 0.08838834764831845f;

  const int sl0 = l15 | (((2 * lhi) & 3) << 4);
  const int sl1 = sl0 | 16;
  const bool hisel = (lhi & 2) != 0;

  const int krow = t >> 3, kd0 = (t & 7) * 16;
  const int vrow = t >> 2, vk0 = (t & 3) * 16;
  s16x8 kr0, kr1, vr0, vr1;
  {
    const u16* p = kb + (size_t)krow * DHEAD + kd0;
    kr0 = *(const s16x8*)p;
    kr1 = *(const s16x8*)(p + 8);
    const u16* pv = vtb + (size_t)vrow * S_LEN + vk0;
    vr0 = *(const s16x8*)pv;
    vr1 = *(const s16x8*)(pv + 8);
  }

  for (int tt = 0; tt < ntiles; ++tt) {
    __syncthreads();
    *(s16x8*)&Ks[KIDX(krow, kd0)] = kr0;
    *(s16x8*)&Ks[KIDX(krow, kd0 + 8)] = kr1;
    *(s16x8*)&Vts[VIDX(vrow, vk0)] = vr0;
    *(s16x8*)&Vts[VIDX(vrow, vk0 + 8)] = vr1;
    __syncthreads();
    if (tt + 1 < ntiles) {
      const u16* p = kb + (size_t)((tt + 1) * 64 + krow) * DHEAD + kd0;
      kr0 = *(const s16x8*)p;
      kr1 = *(const s16x8*)(p + 8);
      const u16* pv = vtb + (size_t)vrow * S_LEN + (tt + 1) * 64 + vk0;
      vr0 = *(const s16x8*)pv;
      vr1 = *(const s16x8*)(pv + 8);
    }

    const int kc_base = tt * 64;
#pragma unroll
    for (int s = 0; s < 2; ++s) {
      const int wmin = qsub[s] * 128 + wave * 16;
      if (kc_base > wmin + 15) continue;
      f32x4 sacc[4];
#pragma unroll
      for (int i = 0; i < 4; ++i) sacc[i] = fz;
      __builtin_amdgcn_s_setprio(1);
#pragma unroll
      for (int ks = 0; ks < 4; ++ks) {
#pragma unroll
        for (int nf = 0; nf < 4; ++nf) {
          s16x8 kf = *(const s16x8*)&Ks[KIDX(nf * 16 + l15, ks * 32 + lhi * 8)];
          sacc[nf] = __builtin_amdgcn_mfma_f32_16x16x32_bf16(kf, qf[s][ks], sacc[nf], 0, 0, 0);
        }
      }
      __builtin_amdgcn_s_setprio(0);

      const int qg = wmin + l15;
      float pmax = -INFINITY;
      if (kc_base + 63 > wmin) {
#pragma unroll
        for (int nf = 0; nf < 4; ++nf)
#pragma unroll
          for (int i = 0; i < 4; ++i) {
            int kv = kc_base + nf * 16 + lhi * 4 + i;
            float sv = sacc[nf][i] * scale;
            sv = (kv <= qg) ? sv : -INFINITY;
            sacc[nf][i] = sv;
            pmax = fmaxf(pmax, sv);
          }
      } else {
#pragma unroll
        for (int nf = 0; nf < 4; ++nf)
#pragma unroll
          for (int i = 0; i < 4; ++i) {
            float sv = sacc[nf][i] * scale;
            sacc[nf][i] = sv;
            pmax = fmaxf(pmax, sv);
          }
      }
      pmax = fmaxf(pmax, __shfl_xor(pmax, 16, 64));
      pmax = fmaxf(pmax, __shfl_xor(pmax, 32, 64));

      if (!__all(pmax <= mrow[s] + 8.0f)) {
        float mnew = fmaxf(mrow[s], pmax);
        float alpha = __expf(mrow[s] - mnew);
        mrow[s] = mnew;
        lsum[s] *= alpha;
#pragma unroll
        for (int i = 0; i < 4; ++i) {
          float al = __shfl(alpha, (lane & 48) | (lhi * 4 + i), 64);
#pragma unroll
          for (int df = 0; df < 8; ++df) acc[s][df][i] *= al;
        }
      }

      float rsum = 0.f;
      unsigned pk[4][2];
#pragma unroll
      for (int nf = 0; nf < 4; ++nf) {
        float p0 = __expf(sacc[nf][0] - mrow[s]);
        float p1 = __expf(sacc[nf][1] - mrow[s]);
        float p2 = __expf(sacc[nf][2] - mrow[s]);
        float p3 = __expf(sacc[nf][3] - mrow[s]);
        rsum += (p0 + p1) + (p2 + p3);
        pk[nf][0] = (unsigned)f2bf(p0) | ((unsigned)f2bf(p1) << 16);
        pk[nf][1] = (unsigned)f2bf(p2) | ((unsigned)f2bf(p3) << 16);
      }
      rsum += __shfl_xor(rsum, 16, 64);
      rsum += __shfl_xor(rsum, 32, 64);
      lsum[s] += rsum;

      s16x8 pa[2];
#pragma unroll
      for (int ph = 0; ph < 2; ++ph) {
        unsigned lo0 = __shfl((int)pk[2 * ph][0], sl0, 64);
        unsigned hi0 = __shfl((int)pk[2 * ph + 1][0], sl0, 64);
        unsigned lo1 = __shfl((int)pk[2 * ph][1], sl0, 64);
        unsigned hi1 = __shfl((int)pk[2 * ph + 1][1], sl0, 64);
        unsigned lo2 = __shfl((int)pk[2 * ph][0], sl1, 64);
        unsigned hi2 = __shfl((int)pk[2 * ph + 1][0], sl1, 64);
        unsigned lo3 = __shfl((int)pk[2 * ph][1], sl1, 64);
        unsigned hi3 = __shfl((int)pk[2 * ph + 1][1], sl1, 64);
        u32x4 w;
        w[0] = hisel ? hi0 : lo0;
        w[1] = hisel ? hi1 : lo1;
        w[2] = hisel ? hi2 : lo2;
        w[3] = hisel ? hi3 : lo3;
        pa[ph] = __builtin_bit_cast(s16x8, w);
      }

      __builtin_amdgcn_s_setprio(1);
#pragma unroll
      for (int ph = 0; ph < 2; ++ph) {
#pragma unroll
        for (int df = 0; df < 8; ++df) {
          s16x8 bb = *(const s16x8*)&Vts[VIDX(df * 16 + l15, ph * 32 + lhi * 8)];
          acc[s][df] = __builtin_amdgcn_mfma_f32_16x16x32_bf16(pa[ph], bb, acc[s][df], 0, 0, 0);
        }
      }
      __builtin_amdgcn_s_setprio(0);
    }
  }

#pragma unroll
  for (int s = 0; s < 2; ++s) {
    float rl = 1.0f / lsum[s];
#pragma unroll
    for (int i = 0; i < 4; ++i) {
      float rli = __shfl(rl, (lane & 48) | (lhi * 4 + i), 64);
      int m = b * S_LEN + qsub[s] * 128 + wave * 16 + lhi * 4 + i;
#pragma unroll
      for (int df = 0; df < 8; ++df) {
        int col = h * DHEAD + df * 16 + l15;
        ctx[(size_t)m * (NH_Q * DHEAD) + col] = f2bf(acc[s][df][i] * rli);
      }
    }
  }
}

extern "C" void kernel_launch(void* const* d_in, const int* in_sizes, int n_in,
                              void* d_out, int out_size, void* d_ws, size_t ws_size,
                              hipStream_t stream) {
  const float* x = (const float*)d_in[0];
  const int* positions = (const int*)d_in[1];
  const float* wq = (const float*)d_in[2];
  const float* wk = (const float*)d_in[3];
  const float* wv = (const float*)d_in[4];
  const float* wo = (const float*)d_in[5];
  float* out = (float*)d_out;

  char* ws = (char*)d_ws;
  const size_t MB1 = 1048576;
  const size_t SZ_X = 33554432;     // 2*2048*4096 bf16
  const size_t SZ_WQKV = 50331648;  // 6144*4096 bf16
  const size_t SZ_Q = 33554432;     // q bf16
  const size_t SZ_WK = 8388608;     // k or v bf16
  const size_t NEED_FULL = MB1 + SZ_X + SZ_WQKV + SZ_Q + 2 * SZ_WK;  // 129 MB

  float* cos_t = (float*)ws;
  float* sin_t = (float*)(ws + MB1 / 2);

  rope_table_kernel<<<512, 256, 0, stream>>>(positions, cos_t, sin_t);

  if (ws_size >= NEED_FULL) {
    char* p = ws + MB1;
    u16* x_bf = (u16*)p;    p += SZ_X;     // later reused as ctx
    u16* wqkv_bf = (u16*)p; p += SZ_WQKV;  // wq|wk|wv stacked; wo after QKV gemm
    u16* q_ws = (u16*)p;    p += SZ_Q;     // q | k | v contiguous
    u16* k_ws = (u16*)p;    p += SZ_WK;
    u16* v_ws = (u16*)p;    p += SZ_WK;
    u16* ctx_ws = x_bf;

    cvt_kernel<<<2048, 256, 0, stream>>>(x, x_bf, 4194304);
    cvt_kernel<<<2048, 256, 0, stream>>>(wq, wqkv_bf, 4194304);
    cvt_kernel<<<1024, 256, 0, stream>>>(wk, wqkv_bf + 16777216, 1048576);
    cvt_kernel<<<1024, 256, 0, stream>>>(wv, wqkv_bf + 20971520, 1048576);

    // fused QKV: N = 6144 (cols 0-4095 Q, 4096-5119 K, 5120-6143 V), 256^2 tile
    gemmdb_kernel<5, 8><<<dim3(24, 16), 512, 0, stream>>>(
        x_bf, wqkv_bf, q_ws, 4096, 6144, 4096, cos_t, sin_t);
    cvt_kernel<<<2048, 256, 0, stream>>>(wo, wqkv_bf, 4194304);  // wqkv_bf now = wo_bf
    attn_kernel<<<dim3(8, 32, 2), 512, 0, stream>>>(q_ws, k_ws, v_ws, ctx_ws);
    // out-proj: 128x256 tile -> 512 blocks, 3 blocks/CU
    gemmdb_kernel<0, 4><<<dim3(16, 32), 512, 0, stream>>>(
        ctx_ws, wqkv_bf, out, 4096, 4096, 4096, nullptr, nullptr);
  } else {
    u16* q_ws = (u16*)(ws + MB1);
    u16* k_ws = (u16*)(ws + MB1 + SZ_Q);
    u16* v_ws = (u16*)(ws + MB1 + SZ_Q + SZ_WK);
    u16* ctx_ws = (u16*)(ws + MB1 + SZ_Q + 2 * SZ_WK);

    gemm_kernel<2, false, false><<<dim3(32, 32), 256, 0, stream>>>(
        x, wq, q_ws, nullptr, 4096, 4096, 4096, cos_t, sin_t, NH_Q);
    gemm_kernel<2, false, false><<<dim3(8, 32), 256, 0, stream>>>(
        x, wk, k_ws, nullptr, 4096, 1024, 4096, cos_t, sin_t, NKV_H);
    gemm_kernel<4, false, false><<<dim3(8, 32), 256, 0, stream>>>(
        x, wv, v_ws, nullptr, 4096, 1024, 4096, nullptr, nullptr, NKV_H);
    attn_kernel<<<dim3(8, 32, 2), 512, 0, stream>>>(q_ws, k_ws, v_ws, ctx_ws);
    gemm_kernel<0, true, false><<<dim3(32, 32), 256, 0, stream>>>(
        ctx_ws, wo, out, nullptr, 4096, 4096, 4096, nullptr, nullptr, 0);
  }
}

// Round 9
// 540.575 us; speedup vs baseline: 1.2364x; 1.1923x over previous
//
#include <hip/hip_runtime.h>
#include <math.h>

typedef short s16x8 __attribute__((ext_vector_type(8)));
typedef float f32x4 __attribute__((ext_vector_type(4)));
typedef unsigned u32x4 __attribute__((ext_vector_type(4)));
typedef unsigned short u16;

#define S_LEN 2048
#define HID_DIM 4096
#define NH_Q 32
#define NKV_H 8
#define DHEAD 128

__device__ __forceinline__ u16 f2bf(float f) {
  unsigned u = __builtin_bit_cast(unsigned, f);
  u += 0x7fffu + ((u >> 16) & 1u);
  return (u16)(u >> 16);
}

// async global -> LDS, 16B per lane; lds base wave-uniform, lane*16 auto-offset
__device__ __forceinline__ void gload16(const u16* g, u16* l) {
  __builtin_amdgcn_global_load_lds(
      (const __attribute__((address_space(1))) void*)g,
      (__attribute__((address_space(3))) void*)l, 16, 0, 0);
}

// ---------------- f32 -> bf16 bulk convert ----------------
__global__ void cvt_kernel(const float* __restrict__ in, u16* __restrict__ out, int n4) {
  int stride = gridDim.x * blockDim.x;
  for (int i = blockIdx.x * blockDim.x + threadIdx.x; i < n4; i += stride) {
    float4 f = ((const float4*)in)[i];
    uint2 o;
    o.x = (unsigned)f2bf(f.x) | ((unsigned)f2bf(f.y) << 16);
    o.y = (unsigned)f2bf(f.z) | ((unsigned)f2bf(f.w) << 16);
    ((uint2*)out)[i] = o;
  }
}

// ---------------- RoPE tables: cos/sin [S][64] ----------------
__global__ void rope_table_kernel(const int* __restrict__ positions,
                                  float* __restrict__ cos_t, float* __restrict__ sin_t) {
  int idx = blockIdx.x * 256 + threadIdx.x;
  if (idx >= S_LEN * 64) return;
  int s = idx >> 6, j = idx & 63;
  float pos = (float)positions[s];
  float inv = expf(-(float)j * (9.210340371976184f / 64.0f));
  float ang = pos * inv;
  float sv, cv;
  sincosf(ang, &sv, &cv);
  cos_t[idx] = cv;
  sin_t[idx] = sv;
}

// ---------------- 8-phase 256^2 GEMM (m201 template): C = A[M][K]*B[N][K]^T ----
// BK=64, 8 waves (2M x 4N), 128KB LDS (2buf x 2half x 16KB x {A,B}), 1 block/CU.
// Per K-tile 4 phases (mfH,nfH) = (0,0),(0,1),(1,1),(1,0); iteration = 2 K-tiles
// = 8 phases; 1 half-tile staged per phase (2 gload_lds); vmcnt(4) at P4/P8 only.
// Wave (wr,wc): rows wr*128 + mf*16 (mf 0..7); cols wc*16 + (nfi&1)*64 +
// (nfi>>1)*128 (nfi 0..3) -> RoPE pairs (j, j+64) in-wave.
// A-half h = rows {h*64+[0,64)} u {128+h*64+[0,64)}; B-half h = C-cols h*128+[0,128).
// Swizzle: 16B-slot phys = logical ^ (row&7); inverse applied on global source.
// EPI: 0 = f32 row-major out; 5 = fused QKV (outp = q; k = q+16777216,
//      v = k+4194304; Q/K RoPE'd [b][h][s][d], V^T [b][h][d][s])
template<int EPI>
__global__ __launch_bounds__(512, 2) void gemm8ph_kernel(
    const u16* __restrict__ A, const u16* __restrict__ B,
    void* __restrict__ outp, int M, int N, int K,
    const float* __restrict__ cos_t, const float* __restrict__ sin_t) {
  __shared__ u16 LDS[65536];  // 128 KB: A at [0,32768), B at [32768,65536) elems
  const int t = threadIdx.x;
  const int wave = t >> 6, lane = t & 63;
  const int l15 = lane & 15, lhi = lane >> 4;
  const int wr = wave >> 2, wc = wave & 3;
  const int gx = gridDim.x;
  const int nwg = gx * gridDim.y;
  const int id = blockIdx.y * gx + blockIdx.x;
  const int swz = (id & 7) * (nwg >> 3) + (id >> 3);
  const int bm = (swz / gx) * 256, bn = (swz % gx) * 256;

  // ---- read-side fragment offsets (conflict-free: slot ^ (l15&7)) ----
  const int sw = l15 & 7;
  int aoff[4][2], boff[2][2];
#pragma unroll
  for (int q = 0; q < 4; ++q)
#pragma unroll
    for (int ks = 0; ks < 2; ++ks)
      aoff[q][ks] = (wr * 64 + q * 16 + l15) * 64 + (((ks << 2) + lhi) ^ sw) * 8;
#pragma unroll
  for (int f = 0; f < 2; ++f)
#pragma unroll
    for (int ks = 0; ks < 2; ++ks)
      boff[f][ks] = (f * 64 + wc * 16 + l15) * 64 + (((ks << 2) + lhi) ^ sw) * 8;

  // ---- staging constants: thread t covers 16B-slots t and t+512 of a half ----
  const int lr1 = t >> 3;            // 0..63
  const int cs1 = ((t & 7) ^ (lr1 & 7)) * 8;  // inverse swizzle (lr2&7 == lr1&7)
  const int rA1 = lr1;               // A local rows [0,64)  -> global +h*64
  const int rA2 = 128 + lr1;         // A local rows [64,128) -> global +128+h*64
  const int ldsw = wave * 512;

  const f32x4 fz = {0.f, 0.f, 0.f, 0.f};
  f32x4 acc[8][4];
#pragma unroll
  for (int mf = 0; mf < 8; ++mf)
#pragma unroll
    for (int nf = 0; nf < 4; ++nf) acc[mf][nf] = fz;

  auto stageA = [&](int tile, int h, int buf) {
    const size_t kb = (size_t)tile * 64;
    gload16(A + (size_t)(bm + h * 64 + rA1) * K + kb + cs1,
            &LDS[buf * 16384 + h * 8192 + ldsw]);
    gload16(A + (size_t)(bm + h * 64 + rA2) * K + kb + cs1,
            &LDS[buf * 16384 + h * 8192 + 4096 + ldsw]);
  };
  auto stageB = [&](int tile, int h, int buf) {
    const size_t kb = (size_t)tile * 64;
    gload16(B + (size_t)(bn + h * 128 + lr1) * K + kb + cs1,
            &LDS[32768 + buf * 16384 + h * 8192 + ldsw]);
    gload16(B + (size_t)(bn + h * 128 + 64 + lr1) * K + kb + cs1,
            &LDS[32768 + buf * 16384 + h * 8192 + 4096 + ldsw]);
  };

  s16x8 afr[4][2], bfr[2][2];
  auto readA = [&](int mfH, int buf) {
    const int base = buf * 16384 + mfH * 8192;
#pragma unroll
    for (int q = 0; q < 4; ++q)
#pragma unroll
      for (int ks = 0; ks < 2; ++ks)
        afr[q][ks] = *(const s16x8*)&LDS[base + aoff[q][ks]];
  };
  auto readB = [&](int nfH, int buf) {
    const int base = 32768 + buf * 16384 + nfH * 8192;
#pragma unroll
    for (int f = 0; f < 2; ++f)
#pragma unroll
      for (int ks = 0; ks < 2; ++ks)
        bfr[f][ks] = *(const s16x8*)&LDS[base + boff[f][ks]];
  };
  auto mfma16 = [&](int mfH, int nfH) {
    __builtin_amdgcn_s_setprio(1);
#pragma unroll
    for (int q = 0; q < 4; ++q)
#pragma unroll
      for (int f = 0; f < 2; ++f)
#pragma unroll
        for (int ks = 0; ks < 2; ++ks)
          acc[mfH * 4 + q][nfH * 2 + f] = __builtin_amdgcn_mfma_f32_16x16x32_bf16(
              afr[q][ks], bfr[f][ks], acc[mfH * 4 + q][nfH * 2 + f], 0, 0, 0);
    __builtin_amdgcn_s_setprio(0);
  };

#define PHASE_SYNC()                        \
  do {                                      \
    __builtin_amdgcn_s_barrier();           \
    asm volatile("s_waitcnt lgkmcnt(0)");   \
    __builtin_amdgcn_sched_barrier(0);      \
  } while (0)

  // ---- prologue: tile0 full + tile1 {A0, B1} (loop P1/P2 provide A1,B0 of t1)
  stageA(0, 0, 0); stageB(0, 0, 0); stageA(0, 1, 0); stageB(0, 1, 0);
  stageA(1, 0, 1); stageB(1, 1, 1);
  asm volatile("s_waitcnt vmcnt(4)");  // tile0 complete; A0(1),B1(1) in flight
  __builtin_amdgcn_sched_barrier(0);
  __builtin_amdgcn_s_barrier();

  const int nt = K >> 6;
  for (int i = 0; i < (nt >> 1); ++i) {
    const int t1 = 2 * i + 1, t2 = 2 * i + 2, t3 = 2 * i + 3;
    const bool s2 = t2 < nt, s3 = t3 < nt;
    // P1 (tile even, buf0): reads A-quad0 + B-pair0; stage A1(t1)->buf1
    readA(0, 0); readB(0, 0); stageA(t1, 1, 1);
    PHASE_SYNC(); mfma16(0, 0); __builtin_amdgcn_s_barrier();
    // P2: reads B-pair1; stage B0(t1)->buf1
    readB(1, 0); stageB(t1, 0, 1);
    PHASE_SYNC(); mfma16(0, 1); __builtin_amdgcn_s_barrier();
    // P3: reads A-quad1; stage A0(t2)->buf0 (A-half0 died at P2)
    readA(1, 0); if (s2) stageA(t2, 0, 0);
    PHASE_SYNC(); mfma16(1, 1); __builtin_amdgcn_s_barrier();
    // P4: reads B-pair0; stage B1(t2)->buf0 (B-half1 died at P3); vmcnt
    readB(0, 0); if (s2) stageB(t2, 1, 0);
    if (s2) { asm volatile("s_waitcnt vmcnt(4)"); }  // tile t1 halves complete
    else    { asm volatile("s_waitcnt vmcnt(0)"); }
    PHASE_SYNC(); mfma16(1, 0); __builtin_amdgcn_s_barrier();
    // P5 (tile odd, buf1): reads A-quad0 + B-pair0; stage A1(t2)->buf0
    readA(0, 1); readB(0, 1); if (s2) stageA(t2, 1, 0);
    PHASE_SYNC(); mfma16(0, 0); __builtin_amdgcn_s_barrier();
    // P6: reads B-pair1; stage B0(t2)->buf0
    readB(1, 1); if (s2) stageB(t2, 0, 0);
    PHASE_SYNC(); mfma16(0, 1); __builtin_amdgcn_s_barrier();
    // P7: reads A-quad1; stage A0(t3)->buf1
    readA(1, 1); if (s3) stageA(t3, 0, 1);
    PHASE_SYNC(); mfma16(1, 1); __builtin_amdgcn_s_barrier();
    // P8: reads B-pair0; stage B1(t3)->buf1; vmcnt
    readB(0, 1); if (s3) stageB(t3, 1, 1);
    if (s3) { asm volatile("s_waitcnt vmcnt(4)"); }  // tile t2 halves complete
    else    { asm volatile("s_waitcnt vmcnt(0)"); }
    PHASE_SYNC(); mfma16(1, 0); __builtin_amdgcn_s_barrier();
  }
#undef PHASE_SYNC

  // ---- epilogue: row = bm + wr*128 + mf*16 + lhi*4 + i;
  //               col = bn + wc*16 + (nfi&1)*64 + (nfi>>1)*128
  if constexpr (EPI == 0) {
    float* C = (float*)outp;
#pragma unroll
    for (int mf = 0; mf < 8; ++mf) {
      int rb = bm + wr * 128 + mf * 16 + lhi * 4;
#pragma unroll
      for (int nfi = 0; nfi < 4; ++nfi) {
        int col = bn + wc * 16 + (nfi & 1) * 64 + (nfi >> 1) * 128 + l15;
#pragma unroll
        for (int i = 0; i < 4; ++i) C[(size_t)(rb + i) * N + col] = acc[mf][nfi][i];
      }
    }
  } else {  // EPI == 5: fused QKV
    u16* qp = (u16*)outp;
    u16* kp = qp + 16777216;  // 2*32*2048*128
    u16* vp = kp + 4194304;   // 2*8*2048*128
    if (bn < 5120) {
      const bool isQ = bn < 4096;
      u16* O = isQ ? qp : kp;
      const int hb = isQ ? (bn >> 7) : ((bn - 4096) >> 7);
      const int Hh = isQ ? NH_Q : NKV_H;
      const int j = wc * 16 + l15;  // 0..63
#pragma unroll
      for (int mf = 0; mf < 8; ++mf) {
        int rb = bm + wr * 128 + mf * 16 + lhi * 4;
#pragma unroll
        for (int p = 0; p < 2; ++p) {
          int head = hb + p;
#pragma unroll
          for (int i = 0; i < 4; ++i) {
            int m = rb + i;
            int b = m >> 11, srw = m & 2047;
            float c = cos_t[srw * 64 + j];
            float s = sin_t[srw * 64 + j];
            float x0 = acc[mf][2 * p][i];
            float x1 = acc[mf][2 * p + 1][i];
            size_t base = ((size_t)(b * Hh + head) * S_LEN + srw) * DHEAD;
            O[base + j] = f2bf(x0 * c - x1 * s);
            O[base + j + 64] = f2bf(x0 * s + x1 * c);
          }
        }
      }
    } else {  // V transposed [b][h][d][s]
#pragma unroll
      for (int mf = 0; mf < 8; ++mf) {
        int rb = bm + wr * 128 + mf * 16 + lhi * 4;
#pragma unroll
        for (int nfi = 0; nfi < 4; ++nfi) {
          int colrel = bn - 5120 + wc * 16 + (nfi & 1) * 64 + (nfi >> 1) * 128 + l15;
          int head = colrel >> 7, d = colrel & 127;
#pragma unroll
          for (int i = 0; i < 4; ++i) {
            int m = rb + i;
            int b = m >> 11, srw = m & 2047;
            vp[((size_t)(b * NKV_H + head) * DHEAD + d) * S_LEN + srw] = f2bf(acc[mf][nfi][i]);
          }
        }
      }
    }
  }
}

// ---------------- reg-staged GEMM (fallback path only) ----------------
template<int EPI, bool ABF16, bool BBF16>
__global__ __launch_bounds__(256) void gemm_kernel(
    const void* __restrict__ Aptr, const void* __restrict__ Bptr,
    void* __restrict__ outp, void* __restrict__ outp2, int M, int N, int K,
    const float* __restrict__ cos_t, const float* __restrict__ sin_t, int Hh) {
  __shared__ u16 As[128][72];
  __shared__ u16 Bs[128][72];
  const int t = threadIdx.x;
  const int wave = t >> 6, lane = t & 63;
  const int l15 = lane & 15, lhi = lane >> 4;
  const int gx = gridDim.x;
  const int nwg = gx * gridDim.y;
  const int id = blockIdx.y * gx + blockIdx.x;
  const int swz = (id & 7) * (nwg >> 3) + (id >> 3);
  const int bm = (swz / gx) * 128, bn = (swz % gx) * 128;

  const f32x4 fz = {0.f, 0.f, 0.f, 0.f};
  f32x4 acc[2][8];
#pragma unroll
  for (int a0 = 0; a0 < 2; ++a0)
#pragma unroll
    for (int b0 = 0; b0 < 8; ++b0) acc[a0][b0] = fz;

  for (int kt = 0; kt < K; kt += 64) {
    __syncthreads();
    if (ABF16) {
      const u16* A = (const u16*)Aptr;
#pragma unroll
      for (int p = 0; p < 4; ++p) {
        int row = p * 32 + (t >> 3), kc = (t & 7) * 8;
        *(s16x8*)&As[row][kc] = *(const s16x8*)(A + (size_t)(bm + row) * K + kt + kc);
      }
    } else {
      const float* A = (const float*)Aptr;
#pragma unroll
      for (int p = 0; p < 8; ++p) {
        int row = p * 16 + (t >> 4), kc = (t & 15) * 4;
        float4 f = *(const float4*)(A + (size_t)(bm + row) * K + kt + kc);
        unsigned* dst = (unsigned*)&As[row][kc];
        dst[0] = (unsigned)f2bf(f.x) | ((unsigned)f2bf(f.y) << 16);
        dst[1] = (unsigned)f2bf(f.z) | ((unsigned)f2bf(f.w) << 16);
      }
    }
    if (BBF16) {
      const u16* Bw = (const u16*)Bptr;
#pragma unroll
      for (int p = 0; p < 4; ++p) {
        int row = p * 32 + (t >> 3), kc = (t & 7) * 8;
        *(s16x8*)&Bs[row][kc] = *(const s16x8*)(Bw + (size_t)(bn + row) * K + kt + kc);
      }
    } else {
      const float* Bw = (const float*)Bptr;
#pragma unroll
      for (int p = 0; p < 8; ++p) {
        int row = p * 16 + (t >> 4), kc = (t & 15) * 4;
        float4 f = *(const float4*)(Bw + (size_t)(bn + row) * K + kt + kc);
        unsigned* dst = (unsigned*)&Bs[row][kc];
        dst[0] = (unsigned)f2bf(f.x) | ((unsigned)f2bf(f.y) << 16);
        dst[1] = (unsigned)f2bf(f.z) | ((unsigned)f2bf(f.w) << 16);
      }
    }
    __syncthreads();
#pragma unroll
    for (int ks = 0; ks < 2; ++ks) {
      s16x8 bfr[8];
#pragma unroll
      for (int nf = 0; nf < 8; ++nf)
        bfr[nf] = *(const s16x8*)&Bs[nf * 16 + l15][ks * 32 + lhi * 8];
#pragma unroll
      for (int mf = 0; mf < 2; ++mf) {
        s16x8 a = *(const s16x8*)&As[wave * 32 + mf * 16 + l15][ks * 32 + lhi * 8];
#pragma unroll
        for (int nf = 0; nf < 8; ++nf)
          acc[mf][nf] = __builtin_amdgcn_mfma_f32_16x16x32_bf16(a, bfr[nf], acc[mf][nf], 0, 0, 0);
      }
    }
  }

  if (EPI == 0) {
    float* C = (float*)outp;
#pragma unroll
    for (int mf = 0; mf < 2; ++mf)
#pragma unroll
      for (int nf = 0; nf < 8; ++nf) {
        int col = bn + nf * 16 + l15;
        int rb = bm + wave * 32 + mf * 16 + lhi * 4;
#pragma unroll
        for (int i = 0; i < 4; ++i) C[(size_t)(rb + i) * N + col] = acc[mf][nf][i];
      }
  } else if (EPI == 2) {
    u16* O = (u16*)outp;
    int h = bn >> 7;
#pragma unroll
    for (int mf = 0; mf < 2; ++mf)
#pragma unroll
      for (int nf = 0; nf < 4; ++nf) {
        int j = nf * 16 + l15;
        int rb = bm + wave * 32 + mf * 16 + lhi * 4;
#pragma unroll
        for (int i = 0; i < 4; ++i) {
          int m = rb + i;
          int b = m >> 11, srow = m & 2047;
          float c = cos_t[srow * 64 + j];
          float s = sin_t[srow * 64 + j];
          float x0 = acc[mf][nf][i];
          float x1 = acc[mf][nf + 4][i];
          size_t base = ((size_t)(b * Hh + h) * S_LEN + srow) * DHEAD;
          O[base + j] = f2bf(x0 * c - x1 * s);
          O[base + j + 64] = f2bf(x0 * s + x1 * c);
        }
      }
  } else {  // EPI == 4: bf16 transposed [b][h][d][s]
    u16* O = (u16*)outp;
#pragma unroll
    for (int mf = 0; mf < 2; ++mf)
#pragma unroll
      for (int nf = 0; nf < 8; ++nf) {
        int col = bn + nf * 16 + l15;
        int h = col >> 7, d = col & 127;
        int rb = bm + wave * 32 + mf * 16 + lhi * 4;
#pragma unroll
        for (int i = 0; i < 4; ++i) {
          int m = rb + i;
          int b = m >> 11, srow = m & 2047;
          O[((size_t)(b * Hh + h) * DHEAD + d) * S_LEN + srow] = f2bf(acc[mf][nf][i]);
        }
      }
  }
}

// ---------------- Flash attention (causal, GQA) ----------------
#define KIDX(r, c) (((r) * 128 + (c)) ^ (((r) & 7) << 3))
#define VIDX(d, kv) (((d) * 64 + (kv)) ^ (((d) & 7) << 3))
__global__ __launch_bounds__(512) void attn_kernel(
    const u16* __restrict__ q, const u16* __restrict__ k, const u16* __restrict__ vt,
    u16* __restrict__ ctx) {
  __shared__ u16 Ks[64 * 128];
  __shared__ u16 Vts[128 * 64];

  const int t = threadIdx.x;
  const int wave = t >> 6, lane = t & 63;
  const int l15 = lane & 15, lhi = lane >> 4;
  const int pi = blockIdx.x, h = blockIdx.y, b = blockIdx.z;
  const int kvh = h >> 2;
  const int qsub[2] = {pi, 15 - pi};
  const int ntiles = 32 - 2 * pi;

  const u16* qb = q + ((size_t)(b * NH_Q + h)) * S_LEN * DHEAD;
  const u16* kb = k + ((size_t)(b * NKV_H + kvh)) * S_LEN * DHEAD;
  const u16* vtb = vt + ((size_t)(b * NKV_H + kvh)) * DHEAD * S_LEN;

  s16x8 qf[2][4];
#pragma unroll
  for (int s = 0; s < 2; ++s)
#pragma unroll
    for (int ks = 0; ks < 4; ++ks)
      qf[s][ks] = *(const s16x8*)(qb + (size_t)(qsub[s] * 128 + wave * 16 + l15) * DHEAD +
                                  ks * 32 + lhi * 8);

  const f32x4 fz = {0.f, 0.f, 0.f, 0.f};
  f32x4 acc[2][8];
#pragma unroll
  for (int s = 0; s < 2; ++s)
#pragma unroll
    for (int i = 0; i < 8; ++i) acc[s][i] = fz;
  float mrow[2] = {-INFINITY, -INFINITY};
  float lsum[2] = {0.f, 0.f};

  const float scale = 0.08838834764831845f;

  const int sl0 = l15 | (((2 * lhi) & 3) << 4);
  const int sl1 = sl0 | 16;
  const bool hisel = (lhi & 2) != 0;

  const int krow = t >> 3, kd0 = (t & 7) * 16;
  const int vrow = t >> 2, vk0 = (t & 3) * 16;
  s16x8 kr0, kr1, vr0, vr1;
  {
    const u16* p = kb + (size_t)krow * DHEAD + kd0;
    kr0 = *(const s16x8*)p;
    kr1 = *(const s16x8*)(p + 8);
    const u16* pv = vtb + (size_t)vrow * S_LEN + vk0;
    vr0 = *(const s16x8*)pv;
    vr1 = *(const s16x8*)(pv + 8);
  }

  for (int tt = 0; tt < ntiles; ++tt) {
    __syncthreads();
    *(s16x8*)&Ks[KIDX(krow, kd0)] = kr0;
    *(s16x8*)&Ks[KIDX(krow, kd0 + 8)] = kr1;
    *(s16x8*)&Vts[VIDX(vrow, vk0)] = vr0;
    *(s16x8*)&Vts[VIDX(vrow, vk0 + 8)] = vr1;
    __syncthreads();
    if (tt + 1 < ntiles) {
      const u16* p = kb + (size_t)((tt + 1) * 64 + krow) * DHEAD + kd0;
      kr0 = *(const s16x8*)p;
      kr1 = *(const s16x8*)(p + 8);
      const u16* pv = vtb + (size_t)vrow * S_LEN + (tt + 1) * 64 + vk0;
      vr0 = *(const s16x8*)pv;
      vr1 = *(const s16x8*)(pv + 8);
    }

    const int kc_base = tt * 64;
#pragma unroll
    for (int s = 0; s < 2; ++s) {
      const int wmin = qsub[s] * 128 + wave * 16;
      if (kc_base > wmin + 15) continue;
      f32x4 sacc[4];
#pragma unroll
      for (int i = 0; i < 4; ++i) sacc[i] = fz;
      __builtin_amdgcn_s_setprio(1);
#pragma unroll
      for (int ks = 0; ks < 4; ++ks) {
#pragma unroll
        for (int nf = 0; nf < 4; ++nf) {
          s16x8 kf = *(const s16x8*)&Ks[KIDX(nf * 16 + l15, ks * 32 + lhi * 8)];
          sacc[nf] = __builtin_amdgcn_mfma_f32_16x16x32_bf16(kf, qf[s][ks], sacc[nf], 0, 0, 0);
        }
      }
      __builtin_amdgcn_s_setprio(0);

      const int qg = wmin + l15;
      float pmax = -INFINITY;
      if (kc_base + 63 > wmin) {
#pragma unroll
        for (int nf = 0; nf < 4; ++nf)
#pragma unroll
          for (int i = 0; i < 4; ++i) {
            int kv = kc_base + nf * 16 + lhi * 4 + i;
            float sv = sacc[nf][i] * scale;
            sv = (kv <= qg) ? sv : -INFINITY;
            sacc[nf][i] = sv;
            pmax = fmaxf(pmax, sv);
          }
      } else {
#pragma unroll
        for (int nf = 0; nf < 4; ++nf)
#pragma unroll
          for (int i = 0; i < 4; ++i) {
            float sv = sacc[nf][i] * scale;
            sacc[nf][i] = sv;
            pmax = fmaxf(pmax, sv);
          }
      }
      pmax = fmaxf(pmax, __shfl_xor(pmax, 16, 64));
      pmax = fmaxf(pmax, __shfl_xor(pmax, 32, 64));

      if (!__all(pmax <= mrow[s] + 8.0f)) {
        float mnew = fmaxf(mrow[s], pmax);
        float alpha = __expf(mrow[s] - mnew);
        mrow[s] = mnew;
        lsum[s] *= alpha;
#pragma unroll
        for (int i = 0; i < 4; ++i) {
          float al = __shfl(alpha, (lane & 48) | (lhi * 4 + i), 64);
#pragma unroll
          for (int df = 0; df < 8; ++df) acc[s][df][i] *= al;
        }
      }

      float rsum = 0.f;
      unsigned pk[4][2];
#pragma unroll
      for (int nf = 0; nf < 4; ++nf) {
        float p0 = __expf(sacc[nf][0] - mrow[s]);
        float p1 = __expf(sacc[nf][1] - mrow[s]);
        float p2 = __expf(sacc[nf][2] - mrow[s]);
        float p3 = __expf(sacc[nf][3] - mrow[s]);
        rsum += (p0 + p1) + (p2 + p3);
        pk[nf][0] = (unsigned)f2bf(p0) | ((unsigned)f2bf(p1) << 16);
        pk[nf][1] = (unsigned)f2bf(p2) | ((unsigned)f2bf(p3) << 16);
      }
      rsum += __shfl_xor(rsum, 16, 64);
      rsum += __shfl_xor(rsum, 32, 64);
      lsum[s] += rsum;

      s16x8 pa[2];
#pragma unroll
      for (int ph = 0; ph < 2; ++ph) {
        unsigned lo0 = __shfl((int)pk[2 * ph][0], sl0, 64);
        unsigned hi0 = __shfl((int)pk[2 * ph + 1][0], sl0, 64);
        unsigned lo1 = __shfl((int)pk[2 * ph][1], sl0, 64);
        unsigned hi1 = __shfl((int)pk[2 * ph + 1][1], sl0, 64);
        unsigned lo2 = __shfl((int)pk[2 * ph][0], sl1, 64);
        unsigned hi2 = __shfl((int)pk[2 * ph + 1][0], sl1, 64);
        unsigned lo3 = __shfl((int)pk[2 * ph][1], sl1, 64);
        unsigned hi3 = __shfl((int)pk[2 * ph + 1][1], sl1, 64);
        u32x4 w;
        w[0] = hisel ? hi0 : lo0;
        w[1] = hisel ? hi1 : lo1;
        w[2] = hisel ? hi2 : lo2;
        w[3] = hisel ? hi3 : lo3;
        pa[ph] = __builtin_bit_cast(s16x8, w);
      }

      __builtin_amdgcn_s_setprio(1);
#pragma unroll
      for (int ph = 0; ph < 2; ++ph) {
#pragma unroll
        for (int df = 0; df < 8; ++df) {
          s16x8 bb = *(const s16x8*)&Vts[VIDX(df * 16 + l15, ph * 32 + lhi * 8)];
          acc[s][df] = __builtin_amdgcn_mfma_f32_16x16x32_bf16(pa[ph], bb, acc[s][df], 0, 0, 0);
        }
      }
      __builtin_amdgcn_s_setprio(0);
    }
  }

#pragma unroll
  for (int s = 0; s < 2; ++s) {
    float rl = 1.0f / lsum[s];
#pragma unroll
    for (int i = 0; i < 4; ++i) {
      float rli = __shfl(rl, (lane & 48) | (lhi * 4 + i), 64);
      int m = b * S_LEN + qsub[s] * 128 + wave * 16 + lhi * 4 + i;
#pragma unroll
      for (int df = 0; df < 8; ++df) {
        int col = h * DHEAD + df * 16 + l15;
        ctx[(size_t)m * (NH_Q * DHEAD) + col] = f2bf(acc[s][df][i] * rli);
      }
    }
  }
}

extern "C" void kernel_launch(void* const* d_in, const int* in_sizes, int n_in,
                              void* d_out, int out_size, void* d_ws, size_t ws_size,
                              hipStream_t stream) {
  const float* x = (const float*)d_in[0];
  const int* positions = (const int*)d_in[1];
  const float* wq = (const float*)d_in[2];
  const float* wk = (const float*)d_in[3];
  const float* wv = (const float*)d_in[4];
  const float* wo = (const float*)d_in[5];
  float* out = (float*)d_out;

  char* ws = (char*)d_ws;
  const size_t MB1 = 1048576;
  const size_t SZ_X = 33554432;     // 2*2048*4096 bf16
  const size_t SZ_WQKV = 50331648;  // 6144*4096 bf16
  const size_t SZ_Q = 33554432;     // q bf16
  const size_t SZ_WK = 8388608;     // k or v bf16
  const size_t NEED_FULL = MB1 + SZ_X + SZ_WQKV + SZ_Q + 2 * SZ_WK;  // 129 MB

  float* cos_t = (float*)ws;
  float* sin_t = (float*)(ws + MB1 / 2);

  rope_table_kernel<<<512, 256, 0, stream>>>(positions, cos_t, sin_t);

  if (ws_size >= NEED_FULL) {
    char* p = ws + MB1;
    u16* x_bf = (u16*)p;    p += SZ_X;     // later reused as ctx
    u16* wqkv_bf = (u16*)p; p += SZ_WQKV;  // wq|wk|wv stacked; wo after QKV gemm
    u16* q_ws = (u16*)p;    p += SZ_Q;     // q | k | v contiguous
    u16* k_ws = (u16*)p;    p += SZ_WK;
    u16* v_ws = (u16*)p;    p += SZ_WK;
    u16* ctx_ws = x_bf;

    cvt_kernel<<<2048, 256, 0, stream>>>(x, x_bf, 4194304);
    cvt_kernel<<<2048, 256, 0, stream>>>(wq, wqkv_bf, 4194304);
    cvt_kernel<<<1024, 256, 0, stream>>>(wk, wqkv_bf + 16777216, 1048576);
    cvt_kernel<<<1024, 256, 0, stream>>>(wv, wqkv_bf + 20971520, 1048576);

    // fused QKV: N = 6144 (cols 0-4095 Q, 4096-5119 K, 5120-6143 V)
    gemm8ph_kernel<5><<<dim3(24, 16), 512, 0, stream>>>(
        x_bf, wqkv_bf, q_ws, 4096, 6144, 4096, cos_t, sin_t);
    cvt_kernel<<<2048, 256, 0, stream>>>(wo, wqkv_bf, 4194304);  // wqkv_bf now = wo_bf
    attn_kernel<<<dim3(8, 32, 2), 512, 0, stream>>>(q_ws, k_ws, v_ws, ctx_ws);
    gemm8ph_kernel<0><<<dim3(16, 16), 512, 0, stream>>>(
        ctx_ws, wqkv_bf, out, 4096, 4096, 4096, nullptr, nullptr);
  } else {
    u16* q_ws = (u16*)(ws + MB1);
    u16* k_ws = (u16*)(ws + MB1 + SZ_Q);
    u16* v_ws = (u16*)(ws + MB1 + SZ_Q + SZ_WK);
    u16* ctx_ws = (u16*)(ws + MB1 + SZ_Q + 2 * SZ_WK);

    gemm_kernel<2, false, false><<<dim3(32, 32), 256, 0, stream>>>(
        x, wq, q_ws, nullptr, 4096, 4096, 4096, cos_t, sin_t, NH_Q);
    gemm_kernel<2, false, false><<<dim3(8, 32), 256, 0, stream>>>(
        x, wk, k_ws, nullptr, 4096, 1024, 4096, cos_t, sin_t, NKV_H);
    gemm_kernel<4, false, false><<<dim3(8, 32), 256, 0, stream>>>(
        x, wv, v_ws, nullptr, 4096, 1024, 4096, nullptr, nullptr, NKV_H);
    attn_kernel<<<dim3(8, 32, 2), 512, 0, stream>>>(q_ws, k_ws, v_ws, ctx_ws);
    gemm_kernel<0, true, false><<<dim3(32, 32), 256, 0, stream>>>(
        ctx_ws, wo, out, nullptr, 4096, 4096, 4096, nullptr, nullptr, 0);
  }
}

// Round 10
// 537.064 us; speedup vs baseline: 1.2444x; 1.0065x over previous
//
#include <hip/hip_runtime.h>
#include <math.h>

typedef short s16x8 __attribute__((ext_vector_type(8)));
typedef float f32x4 __attribute__((ext_vector_type(4)));
typedef unsigned u32x4 __attribute__((ext_vector_type(4)));
typedef unsigned short u16;

#define S_LEN 2048
#define HID_DIM 4096
#define NH_Q 32
#define NKV_H 8
#define DHEAD 128

__device__ __forceinline__ u16 f2bf(float f) {
  unsigned u = __builtin_bit_cast(unsigned, f);
  u += 0x7fffu + ((u >> 16) & 1u);
  return (u16)(u >> 16);
}

// async global -> LDS, 16B per lane; lds base wave-uniform, lane*16 auto-offset
__device__ __forceinline__ void gload16(const u16* g, u16* l) {
  __builtin_amdgcn_global_load_lds(
      (const __attribute__((address_space(1))) void*)g,
      (__attribute__((address_space(3))) void*)l, 16, 0, 0);
}

// ---------------- f32 -> bf16 bulk convert (single region) ----------------
__global__ void cvt_kernel(const float* __restrict__ in, u16* __restrict__ out, int n4) {
  int stride = gridDim.x * blockDim.x;
  for (int i = blockIdx.x * blockDim.x + threadIdx.x; i < n4; i += stride) {
    float4 f = ((const float4*)in)[i];
    uint2 o;
    o.x = (unsigned)f2bf(f.x) | ((unsigned)f2bf(f.y) << 16);
    o.y = (unsigned)f2bf(f.z) | ((unsigned)f2bf(f.w) << 16);
    ((uint2*)out)[i] = o;
  }
}

// ---------------- fused f32 -> bf16 convert: x|wq|wk|wv[|wo] in one launch ----
__global__ void cvt_all_kernel(const float* __restrict__ x, const float* __restrict__ wq,
                               const float* __restrict__ wk, const float* __restrict__ wv,
                               const float* __restrict__ wo, u16* __restrict__ x_bf,
                               u16* __restrict__ wqkv_bf, u16* __restrict__ wo_bf,
                               int with_wo) {
  const int R0 = 4194304, R1 = 8388608, R2 = 9437184, R3 = 10485760, R4 = 14680064;
  const int total = with_wo ? R4 : R3;
  const int stride = gridDim.x * blockDim.x;
  for (int i = blockIdx.x * blockDim.x + threadIdx.x; i < total; i += stride) {
    const float* src;
    u16* dst;
    int off;
    if (i < R0)      { src = x;  dst = x_bf;               off = i; }
    else if (i < R1) { src = wq; dst = wqkv_bf;            off = i - R0; }
    else if (i < R2) { src = wk; dst = wqkv_bf + 16777216; off = i - R1; }
    else if (i < R3) { src = wv; dst = wqkv_bf + 20971520; off = i - R2; }
    else             { src = wo; dst = wo_bf;              off = i - R3; }
    float4 f = ((const float4*)src)[off];
    uint2 o;
    o.x = (unsigned)f2bf(f.x) | ((unsigned)f2bf(f.y) << 16);
    o.y = (unsigned)f2bf(f.z) | ((unsigned)f2bf(f.w) << 16);
    ((uint2*)dst)[off] = o;
  }
}

// ---------------- RoPE tables: cos/sin [S][64] ----------------
__global__ void rope_table_kernel(const int* __restrict__ positions,
                                  float* __restrict__ cos_t, float* __restrict__ sin_t) {
  int idx = blockIdx.x * 256 + threadIdx.x;
  if (idx >= S_LEN * 64) return;
  int s = idx >> 6, j = idx & 63;
  float pos = (float)positions[s];
  float inv = expf(-(float)j * (9.210340371976184f / 64.0f));
  float ang = pos * inv;
  float sv, cv;
  sincosf(ang, &sv, &cv);
  cos_t[idx] = cv;
  sin_t[idx] = sv;
}

// ---------------- 8-phase 256^2 GEMM (m201 template, vmcnt(6) depth): ----
// C = A[M][K]*B[N][K]^T. BK=64, 8 waves (2M x 4N), 128KB LDS, 1 block/CU.
// Per K-tile 4 phases (mfH,nfH) = (0,0),(0,1),(1,1),(1,0); B-half0 fragments
// RETAINED in registers P1->P4 so P4/P8 issue zero ds_reads. Stage order
// (1 half-tile = 2 gload_lds per phase): A1(v) | B0(u+2) | B1(u+2) |
// A0(u+2)+vmcnt(6) | A1(u+2) | B0(v+2) | B1(v+2) | A0(v+2)+vmcnt(6).
// At each wait the 4 oldest in-flight halves == exactly the next 4 phases'
// operands; 3 half-tiles (6 loads) stay in flight (template formula N=2x3).
// All LDS slot overwrites land >=1 full phase after the slot's last read.
// EPI: 0 = f32 row-major out; 5 = fused QKV (outp = q; k = q+16777216,
//      v = k+4194304; Q/K RoPE'd [b][h][s][d], V^T [b][h][d][s])
template<int EPI>
__global__ __launch_bounds__(512, 2) void gemm8ph_kernel(
    const u16* __restrict__ A, const u16* __restrict__ B,
    void* __restrict__ outp, int M, int N, int K,
    const float* __restrict__ cos_t, const float* __restrict__ sin_t) {
  __shared__ u16 LDS[65536];  // 128 KB: A at [0,32768), B at [32768,65536) elems
  const int t = threadIdx.x;
  const int wave = t >> 6, lane = t & 63;
  const int l15 = lane & 15, lhi = lane >> 4;
  const int wr = wave >> 2, wc = wave & 3;
  const int gx = gridDim.x;
  const int nwg = gx * gridDim.y;
  const int id = blockIdx.y * gx + blockIdx.x;
  const int swz = (id & 7) * (nwg >> 3) + (id >> 3);
  const int bm = (swz / gx) * 256, bn = (swz % gx) * 256;

  // ---- read-side fragment offsets (conflict-free: slot ^ (l15&7)) ----
  const int sw = l15 & 7;
  int aoff[4][2], boff[2][2];
#pragma unroll
  for (int q = 0; q < 4; ++q)
#pragma unroll
    for (int ks = 0; ks < 2; ++ks)
      aoff[q][ks] = (wr * 64 + q * 16 + l15) * 64 + (((ks << 2) + lhi) ^ sw) * 8;
#pragma unroll
  for (int f = 0; f < 2; ++f)
#pragma unroll
    for (int ks = 0; ks < 2; ++ks)
      boff[f][ks] = (f * 64 + wc * 16 + l15) * 64 + (((ks << 2) + lhi) ^ sw) * 8;

  // ---- staging constants: thread t covers 16B-slots t and t+512 of a half ----
  const int lr1 = t >> 3;                     // 0..63
  const int cs1 = ((t & 7) ^ (lr1 & 7)) * 8;  // inverse swizzle
  const int rA1 = lr1;
  const int rA2 = 128 + lr1;
  const int ldsw = wave * 512;

  const f32x4 fz = {0.f, 0.f, 0.f, 0.f};
  f32x4 acc[8][4];
#pragma unroll
  for (int mf = 0; mf < 8; ++mf)
#pragma unroll
    for (int nf = 0; nf < 4; ++nf) acc[mf][nf] = fz;

  auto stageA = [&](int tile, int h, int buf) {
    const size_t kb = (size_t)tile * 64;
    gload16(A + (size_t)(bm + h * 64 + rA1) * K + kb + cs1,
            &LDS[buf * 16384 + h * 8192 + ldsw]);
    gload16(A + (size_t)(bm + h * 64 + rA2) * K + kb + cs1,
            &LDS[buf * 16384 + h * 8192 + 4096 + ldsw]);
  };
  auto stageB = [&](int tile, int h, int buf) {
    const size_t kb = (size_t)tile * 64;
    gload16(B + (size_t)(bn + h * 128 + lr1) * K + kb + cs1,
            &LDS[32768 + buf * 16384 + h * 8192 + ldsw]);
    gload16(B + (size_t)(bn + h * 128 + 64 + lr1) * K + kb + cs1,
            &LDS[32768 + buf * 16384 + h * 8192 + 4096 + ldsw]);
  };

  s16x8 afr[4][2], bfr[2][2], bfrK[2][2];  // bfrK: B-half0, retained P1->P4
  auto readA = [&](int mfH, int buf) {
    const int base = buf * 16384 + mfH * 8192;
#pragma unroll
    for (int q = 0; q < 4; ++q)
#pragma unroll
      for (int ks = 0; ks < 2; ++ks)
        afr[q][ks] = *(const s16x8*)&LDS[base + aoff[q][ks]];
  };
  auto readB = [&](int nfH, int buf, s16x8 (&dst)[2][2]) {
    const int base = 32768 + buf * 16384 + nfH * 8192;
#pragma unroll
    for (int f = 0; f < 2; ++f)
#pragma unroll
      for (int ks = 0; ks < 2; ++ks)
        dst[f][ks] = *(const s16x8*)&LDS[base + boff[f][ks]];
  };
  auto mfma16 = [&](int mfH, int nfH, const s16x8 (&bb)[2][2]) {
    __builtin_amdgcn_s_setprio(1);
#pragma unroll
    for (int q = 0; q < 4; ++q)
#pragma unroll
      for (int f = 0; f < 2; ++f)
#pragma unroll
        for (int ks = 0; ks < 2; ++ks)
          acc[mfH * 4 + q][nfH * 2 + f] = __builtin_amdgcn_mfma_f32_16x16x32_bf16(
              afr[q][ks], bb[f][ks], acc[mfH * 4 + q][nfH * 2 + f], 0, 0, 0);
    __builtin_amdgcn_s_setprio(0);
  };

#define PHASE_SYNC()                        \
  do {                                      \
    __builtin_amdgcn_s_barrier();           \
    asm volatile("s_waitcnt lgkmcnt(0)");   \
    __builtin_amdgcn_sched_barrier(0);      \
  } while (0)

  // ---- prologue: tile0 {A0,B0,B1,A1} + tile1 {A0,B0,B1} (A1(t1) at P1) ----
  stageA(0, 0, 0); stageB(0, 0, 0); stageB(0, 1, 0); stageA(0, 1, 0);
  stageA(1, 0, 1); stageB(1, 0, 1); stageB(1, 1, 1);
  asm volatile("s_waitcnt vmcnt(6)");  // tile0 complete; t1's 3 halves in flight
  __builtin_amdgcn_sched_barrier(0);
  __builtin_amdgcn_s_barrier();

  const int nt = K >> 6;
  for (int i = 0; i < (nt >> 1); ++i) {
    const int u = 2 * i, v = 2 * i + 1;
    const bool s2 = (u + 2) < nt;  // == (v+2 < nt) for even nt
    // P1 (tile u, buf0): reads A0 + B0(->bfrK, kept to P4); stage A1(v)->buf1
    readA(0, 0); readB(0, 0, bfrK); stageA(v, 1, 1);
    PHASE_SYNC(); mfma16(0, 0, bfrK); __builtin_amdgcn_s_barrier();
    // P2: reads B1; stage B0(u+2)->buf0 (B0(u) slot free; frags live in bfrK)
    readB(1, 0, bfr); if (s2) stageB(u + 2, 0, 0);
    PHASE_SYNC(); mfma16(0, 1, bfr); __builtin_amdgcn_s_barrier();
    // P3: reads A1; stage B1(u+2)->buf0
    readA(1, 0); if (s2) stageB(u + 2, 1, 0);
    PHASE_SYNC(); mfma16(1, 1, bfr); __builtin_amdgcn_s_barrier();
    // P4: zero reads (A1 in afr, B0 in bfrK); stage A0(u+2)->buf0; wait
    if (s2) { stageA(u + 2, 0, 0); asm volatile("s_waitcnt vmcnt(6)"); }
    else    { asm volatile("s_waitcnt vmcnt(0)"); }
    PHASE_SYNC(); mfma16(1, 0, bfrK); __builtin_amdgcn_s_barrier();
    // P5 (tile v, buf1): reads A0 + B0(->bfrK); stage A1(u+2)->buf0
    readA(0, 1); readB(0, 1, bfrK); if (s2) stageA(u + 2, 1, 0);
    PHASE_SYNC(); mfma16(0, 0, bfrK); __builtin_amdgcn_s_barrier();
    // P6: reads B1; stage B0(v+2)->buf1
    readB(1, 1, bfr); if (s2) stageB(v + 2, 0, 1);
    PHASE_SYNC(); mfma16(0, 1, bfr); __builtin_amdgcn_s_barrier();
    // P7: reads A1; stage B1(v+2)->buf1
    readA(1, 1); if (s2) stageB(v + 2, 1, 1);
    PHASE_SYNC(); mfma16(1, 1, bfr); __builtin_amdgcn_s_barrier();
    // P8: zero reads; stage A0(v+2)->buf1; wait
    if (s2) { stageA(v + 2, 0, 1); asm volatile("s_waitcnt vmcnt(6)"); }
    else    { asm volatile("s_waitcnt vmcnt(0)"); }
    PHASE_SYNC(); mfma16(1, 0, bfrK); __builtin_amdgcn_s_barrier();
  }
#undef PHASE_SYNC

  // ---- epilogue: row = bm + wr*128 + mf*16 + lhi*4 + i;
  //               col = bn + wc*16 + (nfi&1)*64 + (nfi>>1)*128
  if constexpr (EPI == 0) {
    float* C = (float*)outp;
#pragma unroll
    for (int mf = 0; mf < 8; ++mf) {
      int rb = bm + wr * 128 + mf * 16 + lhi * 4;
#pragma unroll
      for (int nfi = 0; nfi < 4; ++nfi) {
        int col = bn + wc * 16 + (nfi & 1) * 64 + (nfi >> 1) * 128 + l15;
#pragma unroll
        for (int i = 0; i < 4; ++i) C[(size_t)(rb + i) * N + col] = acc[mf][nfi][i];
      }
    }
  } else {  // EPI == 5: fused QKV
    u16* qp = (u16*)outp;
    u16* kp = qp + 16777216;  // 2*32*2048*128
    u16* vp = kp + 4194304;   // 2*8*2048*128
    if (bn < 5120) {
      const bool isQ = bn < 4096;
      u16* O = isQ ? qp : kp;
      const int hb = isQ ? (bn >> 7) : ((bn - 4096) >> 7);
      const int Hh = isQ ? NH_Q : NKV_H;
      const int j = wc * 16 + l15;  // 0..63
#pragma unroll
      for (int mf = 0; mf < 8; ++mf) {
        int rb = bm + wr * 128 + mf * 16 + lhi * 4;
#pragma unroll
        for (int p = 0; p < 2; ++p) {
          int head = hb + p;
#pragma unroll
          for (int i = 0; i < 4; ++i) {
            int m = rb + i;
            int b = m >> 11, srw = m & 2047;
            float c = cos_t[srw * 64 + j];
            float s = sin_t[srw * 64 + j];
            float x0 = acc[mf][2 * p][i];
            float x1 = acc[mf][2 * p + 1][i];
            size_t base = ((size_t)(b * Hh + head) * S_LEN + srw) * DHEAD;
            O[base + j] = f2bf(x0 * c - x1 * s);
            O[base + j + 64] = f2bf(x0 * s + x1 * c);
          }
        }
      }
    } else {  // V transposed [b][h][d][s]
#pragma unroll
      for (int mf = 0; mf < 8; ++mf) {
        int rb = bm + wr * 128 + mf * 16 + lhi * 4;
#pragma unroll
        for (int nfi = 0; nfi < 4; ++nfi) {
          int colrel = bn - 5120 + wc * 16 + (nfi & 1) * 64 + (nfi >> 1) * 128 + l15;
          int head = colrel >> 7, d = colrel & 127;
#pragma unroll
          for (int i = 0; i < 4; ++i) {
            int m = rb + i;
            int b = m >> 11, srw = m & 2047;
            vp[((size_t)(b * NKV_H + head) * DHEAD + d) * S_LEN + srw] = f2bf(acc[mf][nfi][i]);
          }
        }
      }
    }
  }
}

// ---------------- reg-staged GEMM (fallback path only) ----------------
template<int EPI, bool ABF16, bool BBF16>
__global__ __launch_bounds__(256) void gemm_kernel(
    const void* __restrict__ Aptr, const void* __restrict__ Bptr,
    void* __restrict__ outp, void* __restrict__ outp2, int M, int N, int K,
    const float* __restrict__ cos_t, const float* __restrict__ sin_t, int Hh) {
  __shared__ u16 As[128][72];
  __shared__ u16 Bs[128][72];
  const int t = threadIdx.x;
  const int wave = t >> 6, lane = t & 63;
  const int l15 = lane & 15, lhi = lane >> 4;
  const int gx = gridDim.x;
  const int nwg = gx * gridDim.y;
  const int id = blockIdx.y * gx + blockIdx.x;
  const int swz = (id & 7) * (nwg >> 3) + (id >> 3);
  const int bm = (swz / gx) * 128, bn = (swz % gx) * 128;

  const f32x4 fz = {0.f, 0.f, 0.f, 0.f};
  f32x4 acc[2][8];
#pragma unroll
  for (int a0 = 0; a0 < 2; ++a0)
#pragma unroll
    for (int b0 = 0; b0 < 8; ++b0) acc[a0][b0] = fz;

  for (int kt = 0; kt < K; kt += 64) {
    __syncthreads();
    if (ABF16) {
      const u16* A = (const u16*)Aptr;
#pragma unroll
      for (int p = 0; p < 4; ++p) {
        int row = p * 32 + (t >> 3), kc = (t & 7) * 8;
        *(s16x8*)&As[row][kc] = *(const s16x8*)(A + (size_t)(bm + row) * K + kt + kc);
      }
    } else {
      const float* A = (const float*)Aptr;
#pragma unroll
      for (int p = 0; p < 8; ++p) {
        int row = p * 16 + (t >> 4), kc = (t & 15) * 4;
        float4 f = *(const float4*)(A + (size_t)(bm + row) * K + kt + kc);
        unsigned* dst = (unsigned*)&As[row][kc];
        dst[0] = (unsigned)f2bf(f.x) | ((unsigned)f2bf(f.y) << 16);
        dst[1] = (unsigned)f2bf(f.z) | ((unsigned)f2bf(f.w) << 16);
      }
    }
    if (BBF16) {
      const u16* Bw = (const u16*)Bptr;
#pragma unroll
      for (int p = 0; p < 4; ++p) {
        int row = p * 32 + (t >> 3), kc = (t & 7) * 8;
        *(s16x8*)&Bs[row][kc] = *(const s16x8*)(Bw + (size_t)(bn + row) * K + kt + kc);
      }
    } else {
      const float* Bw = (const float*)Bptr;
#pragma unroll
      for (int p = 0; p < 8; ++p) {
        int row = p * 16 + (t >> 4), kc = (t & 15) * 4;
        float4 f = *(const float4*)(Bw + (size_t)(bn + row) * K + kt + kc);
        unsigned* dst = (unsigned*)&Bs[row][kc];
        dst[0] = (unsigned)f2bf(f.x) | ((unsigned)f2bf(f.y) << 16);
        dst[1] = (unsigned)f2bf(f.z) | ((unsigned)f2bf(f.w) << 16);
      }
    }
    __syncthreads();
#pragma unroll
    for (int ks = 0; ks < 2; ++ks) {
      s16x8 bfr[8];
#pragma unroll
      for (int nf = 0; nf < 8; ++nf)
        bfr[nf] = *(const s16x8*)&Bs[nf * 16 + l15][ks * 32 + lhi * 8];
#pragma unroll
      for (int mf = 0; mf < 2; ++mf) {
        s16x8 a = *(const s16x8*)&As[wave * 32 + mf * 16 + l15][ks * 32 + lhi * 8];
#pragma unroll
        for (int nf = 0; nf < 8; ++nf)
          acc[mf][nf] = __builtin_amdgcn_mfma_f32_16x16x32_bf16(a, bfr[nf], acc[mf][nf], 0, 0, 0);
      }
    }
  }

  if (EPI == 0) {
    float* C = (float*)outp;
#pragma unroll
    for (int mf = 0; mf < 2; ++mf)
#pragma unroll
      for (int nf = 0; nf < 8; ++nf) {
        int col = bn + nf * 16 + l15;
        int rb = bm + wave * 32 + mf * 16 + lhi * 4;
#pragma unroll
        for (int i = 0; i < 4; ++i) C[(size_t)(rb + i) * N + col] = acc[mf][nf][i];
      }
  } else if (EPI == 2) {
    u16* O = (u16*)outp;
    int h = bn >> 7;
#pragma unroll
    for (int mf = 0; mf < 2; ++mf)
#pragma unroll
      for (int nf = 0; nf < 4; ++nf) {
        int j = nf * 16 + l15;
        int rb = bm + wave * 32 + mf * 16 + lhi * 4;
#pragma unroll
        for (int i = 0; i < 4; ++i) {
          int m = rb + i;
          int b = m >> 11, srow = m & 2047;
          float c = cos_t[srow * 64 + j];
          float s = sin_t[srow * 64 + j];
          float x0 = acc[mf][nf][i];
          float x1 = acc[mf][nf + 4][i];
          size_t base = ((size_t)(b * Hh + h) * S_LEN + srow) * DHEAD;
          O[base + j] = f2bf(x0 * c - x1 * s);
          O[base + j + 64] = f2bf(x0 * s + x1 * c);
        }
      }
  } else {  // EPI == 4: bf16 transposed [b][h][d][s]
    u16* O = (u16*)outp;
#pragma unroll
    for (int mf = 0; mf < 2; ++mf)
#pragma unroll
      for (int nf = 0; nf < 8; ++nf) {
        int col = bn + nf * 16 + l15;
        int h = col >> 7, d = col & 127;
        int rb = bm + wave * 32 + mf * 16 + lhi * 4;
#pragma unroll
        for (int i = 0; i < 4; ++i) {
          int m = rb + i;
          int b = m >> 11, srow = m & 2047;
          O[((size_t)(b * Hh + h) * DHEAD + d) * S_LEN + srow] = f2bf(acc[mf][nf][i]);
        }
      }
  }
}

// ---------------- Flash attention (causal, GQA) ----------------
#define KIDX(r, c) (((r) * 128 + (c)) ^ (((r) & 7) << 3))
#define VIDX(d, kv) (((d) * 64 + (kv)) ^ (((d) & 7) << 3))
__global__ __launch_bounds__(512) void attn_kernel(
    const u16* __restrict__ q, const u16* __restrict__ k, const u16* __restrict__ vt,
    u16* __restrict__ ctx) {
  __shared__ u16 Ks[64 * 128];
  __shared__ u16 Vts[128 * 64];

  const int t = threadIdx.x;
  const int wave = t >> 6, lane = t & 63;
  const int l15 = lane & 15, lhi = lane >> 4;
  const int pi = blockIdx.x, h = blockIdx.y, b = blockIdx.z;
  const int kvh = h >> 2;
  const int qsub[2] = {pi, 15 - pi};
  const int ntiles = 32 - 2 * pi;

  const u16* qb = q + ((size_t)(b * NH_Q + h)) * S_LEN * DHEAD;
  const u16* kb = k + ((size_t)(b * NKV_H + kvh)) * S_LEN * DHEAD;
  const u16* vtb = vt + ((size_t)(b * NKV_H + kvh)) * DHEAD * S_LEN;

  s16x8 qf[2][4];
#pragma unroll
  for (int s = 0; s < 2; ++s)
#pragma unroll
    for (int ks = 0; ks < 4; ++ks)
      qf[s][ks] = *(const s16x8*)(qb + (size_t)(qsub[s] * 128 + wave * 16 + l15) * DHEAD +
                                  ks * 32 + lhi * 8);

  const f32x4 fz = {0.f, 0.f, 0.f, 0.f};
  f32x4 acc[2][8];
#pragma unroll
  for (int s = 0; s < 2; ++s)
#pragma unroll
    for (int i = 0; i < 8; ++i) acc[s][i] = fz;
  float mrow[2] = {-INFINITY, -INFINITY};
  float lsum[2] = {0.f, 0.f};

  const float scale = 0.08838834764831845f;

  const int sl0 = l15 | (((2 * lhi) & 3) << 4);
  const int sl1 = sl0 | 16;
  const bool hisel = (lhi & 2) != 0;

  const int krow = t >> 3, kd0 = (t & 7) * 16;
  const int vrow = t >> 2, vk0 = (t & 3) * 16;
  s16x8 kr0, kr1, vr0, vr1;
  {
    const u16* p = kb + (size_t)krow * DHEAD + kd0;
    kr0 = *(const s16x8*)p;
    kr1 = *(const s16x8*)(p + 8);
    const u16* pv = vtb + (size_t)vrow * S_LEN + vk0;
    vr0 = *(const s16x8*)pv;
    vr1 = *(const s16x8*)(pv + 8);
  }

  for (int tt = 0; tt < ntiles; ++tt) {
    __syncthreads();
    *(s16x8*)&Ks[KIDX(krow, kd0)] = kr0;
    *(s16x8*)&Ks[KIDX(krow, kd0 + 8)] = kr1;
    *(s16x8*)&Vts[VIDX(vrow, vk0)] = vr0;
    *(s16x8*)&Vts[VIDX(vrow, vk0 + 8)] = vr1;
    __syncthreads();
    if (tt + 1 < ntiles) {
      const u16* p = kb + (size_t)((tt + 1) * 64 + krow) * DHEAD + kd0;
      kr0 = *(const s16x8*)p;
      kr1 = *(const s16x8*)(p + 8);
      const u16* pv = vtb + (size_t)vrow * S_LEN + (tt + 1) * 64 + vk0;
      vr0 = *(const s16x8*)pv;
      vr1 = *(const s16x8*)(pv + 8);
    }

    const int kc_base = tt * 64;
#pragma unroll
    for (int s = 0; s < 2; ++s) {
      const int wmin = qsub[s] * 128 + wave * 16;
      if (kc_base > wmin + 15) continue;
      f32x4 sacc[4];
#pragma unroll
      for (int i = 0; i < 4; ++i) sacc[i] = fz;
      __builtin_amdgcn_s_setprio(1);
#pragma unroll
      for (int ks = 0; ks < 4; ++ks) {
#pragma unroll
        for (int nf = 0; nf < 4; ++nf) {
          s16x8 kf = *(const s16x8*)&Ks[KIDX(nf * 16 + l15, ks * 32 + lhi * 8)];
          sacc[nf] = __builtin_amdgcn_mfma_f32_16x16x32_bf16(kf, qf[s][ks], sacc[nf], 0, 0, 0);
        }
      }
      __builtin_amdgcn_s_setprio(0);

      const int qg = wmin + l15;
      float pmax = -INFINITY;
      if (kc_base + 63 > wmin) {
#pragma unroll
        for (int nf = 0; nf < 4; ++nf)
#pragma unroll
          for (int i = 0; i < 4; ++i) {
            int kv = kc_base + nf * 16 + lhi * 4 + i;
            float sv = sacc[nf][i] * scale;
            sv = (kv <= qg) ? sv : -INFINITY;
            sacc[nf][i] = sv;
            pmax = fmaxf(pmax, sv);
          }
      } else {
#pragma unroll
        for (int nf = 0; nf < 4; ++nf)
#pragma unroll
          for (int i = 0; i < 4; ++i) {
            float sv = sacc[nf][i] * scale;
            sacc[nf][i] = sv;
            pmax = fmaxf(pmax, sv);
          }
      }
      pmax = fmaxf(pmax, __shfl_xor(pmax, 16, 64));
      pmax = fmaxf(pmax, __shfl_xor(pmax, 32, 64));

      if (!__all(pmax <= mrow[s] + 8.0f)) {
        float mnew = fmaxf(mrow[s], pmax);
        float alpha = __expf(mrow[s] - mnew);
        mrow[s] = mnew;
        lsum[s] *= alpha;
#pragma unroll
        for (int i = 0; i < 4; ++i) {
          float al = __shfl(alpha, (lane & 48) | (lhi * 4 + i), 64);
#pragma unroll
          for (int df = 0; df < 8; ++df) acc[s][df][i] *= al;
        }
      }

      float rsum = 0.f;
      unsigned pk[4][2];
#pragma unroll
      for (int nf = 0; nf < 4; ++nf) {
        float p0 = __expf(sacc[nf][0] - mrow[s]);
        float p1 = __expf(sacc[nf][1] - mrow[s]);
        float p2 = __expf(sacc[nf][2] - mrow[s]);
        float p3 = __expf(sacc[nf][3] - mrow[s]);
        rsum += (p0 + p1) + (p2 + p3);
        pk[nf][0] = (unsigned)f2bf(p0) | ((unsigned)f2bf(p1) << 16);
        pk[nf][1] = (unsigned)f2bf(p2) | ((unsigned)f2bf(p3) << 16);
      }
      rsum += __shfl_xor(rsum, 16, 64);
      rsum += __shfl_xor(rsum, 32, 64);
      lsum[s] += rsum;

      s16x8 pa[2];
#pragma unroll
      for (int ph = 0; ph < 2; ++ph) {
        unsigned lo0 = __shfl((int)pk[2 * ph][0], sl0, 64);
        unsigned hi0 = __shfl((int)pk[2 * ph + 1][0], sl0, 64);
        unsigned lo1 = __shfl((int)pk[2 * ph][1], sl0, 64);
        unsigned hi1 = __shfl((int)pk[2 * ph + 1][1], sl0, 64);
        unsigned lo2 = __shfl((int)pk[2 * ph][0], sl1, 64);
        unsigned hi2 = __shfl((int)pk[2 * ph + 1][0], sl1, 64);
        unsigned lo3 = __shfl((int)pk[2 * ph][1], sl1, 64);
        unsigned hi3 = __shfl((int)pk[2 * ph + 1][1], sl1, 64);
        u32x4 w;
        w[0] = hisel ? hi0 : lo0;
        w[1] = hisel ? hi1 : lo1;
        w[2] = hisel ? hi2 : lo2;
        w[3] = hisel ? hi3 : lo3;
        pa[ph] = __builtin_bit_cast(s16x8, w);
      }

      __builtin_amdgcn_s_setprio(1);
#pragma unroll
      for (int ph = 0; ph < 2; ++ph) {
#pragma unroll
        for (int df = 0; df < 8; ++df) {
          s16x8 bb = *(const s16x8*)&Vts[VIDX(df * 16 + l15, ph * 32 + lhi * 8)];
          acc[s][df] = __builtin_amdgcn_mfma_f32_16x16x32_bf16(pa[ph], bb, acc[s][df], 0, 0, 0);
        }
      }
      __builtin_amdgcn_s_setprio(0);
    }
  }

#pragma unroll
  for (int s = 0; s < 2; ++s) {
    float rl = 1.0f / lsum[s];
#pragma unroll
    for (int i = 0; i < 4; ++i) {
      float rli = __shfl(rl, (lane & 48) | (lhi * 4 + i), 64);
      int m = b * S_LEN + qsub[s] * 128 + wave * 16 + lhi * 4 + i;
#pragma unroll
      for (int df = 0; df < 8; ++df) {
        int col = h * DHEAD + df * 16 + l15;
        ctx[(size_t)m * (NH_Q * DHEAD) + col] = f2bf(acc[s][df][i] * rli);
      }
    }
  }
}

extern "C" void kernel_launch(void* const* d_in, const int* in_sizes, int n_in,
                              void* d_out, int out_size, void* d_ws, size_t ws_size,
                              hipStream_t stream) {
  const float* x = (const float*)d_in[0];
  const int* positions = (const int*)d_in[1];
  const float* wq = (const float*)d_in[2];
  const float* wk = (const float*)d_in[3];
  const float* wv = (const float*)d_in[4];
  const float* wo = (const float*)d_in[5];
  float* out = (float*)d_out;

  char* ws = (char*)d_ws;
  const size_t MB1 = 1048576;
  const size_t SZ_X = 33554432;     // 2*2048*4096 bf16
  const size_t SZ_WQKV = 50331648;  // 6144*4096 bf16
  const size_t SZ_WO = 33554432;    // 4096*4096 bf16
  const size_t SZ_Q = 33554432;     // q bf16
  const size_t SZ_WK = 8388608;     // k or v bf16
  const size_t NEED_FULL = MB1 + SZ_X + SZ_WQKV + SZ_Q + 2 * SZ_WK;  // 129 MB
  const size_t NEED_WO = NEED_FULL + SZ_WO;                          // 161 MB

  float* cos_t = (float*)ws;
  float* sin_t = (float*)(ws + MB1 / 2);

  rope_table_kernel<<<512, 256, 0, stream>>>(positions, cos_t, sin_t);

  if (ws_size >= NEED_WO) {
    // -------- preferred: all converts fused in one launch, wo_bf separate --------
    char* p = ws + MB1;
    u16* x_bf = (u16*)p;    p += SZ_X;     // later reused as ctx
    u16* wqkv_bf = (u16*)p; p += SZ_WQKV;  // wq|wk|wv stacked
    u16* wo_bf = (u16*)p;   p += SZ_WO;
    u16* q_ws = (u16*)p;    p += SZ_Q;     // q | k | v contiguous
    u16* k_ws = (u16*)p;    p += SZ_WK;
    u16* v_ws = (u16*)p;    p += SZ_WK;
    u16* ctx_ws = x_bf;

    cvt_all_kernel<<<2048, 256, 0, stream>>>(x, wq, wk, wv, wo, x_bf, wqkv_bf, wo_bf, 1);
    gemm8ph_kernel<5><<<dim3(24, 16), 512, 0, stream>>>(
        x_bf, wqkv_bf, q_ws, 4096, 6144, 4096, cos_t, sin_t);
    attn_kernel<<<dim3(8, 32, 2), 512, 0, stream>>>(q_ws, k_ws, v_ws, ctx_ws);
    gemm8ph_kernel<0><<<dim3(16, 16), 512, 0, stream>>>(
        ctx_ws, wo_bf, out, 4096, 4096, 4096, nullptr, nullptr);
  } else if (ws_size >= NEED_FULL) {
    // -------- 129 MB: wo_bf overwrites wqkv_bf after the QKV GEMM --------
    char* p = ws + MB1;
    u16* x_bf = (u16*)p;    p += SZ_X;
    u16* wqkv_bf = (u16*)p; p += SZ_WQKV;
    u16* q_ws = (u16*)p;    p += SZ_Q;
    u16* k_ws = (u16*)p;    p += SZ_WK;
    u16* v_ws = (u16*)p;    p += SZ_WK;
    u16* ctx_ws = x_bf;

    cvt_all_kernel<<<2048, 256, 0, stream>>>(x, wq, wk, wv, nullptr, x_bf, wqkv_bf, nullptr, 0);
    gemm8ph_kernel<5><<<dim3(24, 16), 512, 0, stream>>>(
        x_bf, wqkv_bf, q_ws, 4096, 6144, 4096, cos_t, sin_t);
    cvt_kernel<<<2048, 256, 0, stream>>>(wo, wqkv_bf, 4194304);  // wqkv_bf now = wo_bf
    attn_kernel<<<dim3(8, 32, 2), 512, 0, stream>>>(q_ws, k_ws, v_ws, ctx_ws);
    gemm8ph_kernel<0><<<dim3(16, 16), 512, 0, stream>>>(
        ctx_ws, wqkv_bf, out, 4096, 4096, 4096, nullptr, nullptr);
  } else {
    u16* q_ws = (u16*)(ws + MB1);
    u16* k_ws = (u16*)(ws + MB1 + SZ_Q);
    u16* v_ws = (u16*)(ws + MB1 + SZ_Q + SZ_WK);
    u16* ctx_ws = (u16*)(ws + MB1 + SZ_Q + 2 * SZ_WK);

    gemm_kernel<2, false, false><<<dim3(32, 32), 256, 0, stream>>>(
        x, wq, q_ws, nullptr, 4096, 4096, 4096, cos_t, sin_t, NH_Q);
    gemm_kernel<2, false, false><<<dim3(8, 32), 256, 0, stream>>>(
        x, wk, k_ws, nullptr, 4096, 1024, 4096, cos_t, sin_t, NKV_H);
    gemm_kernel<4, false, false><<<dim3(8, 32), 256, 0, stream>>>(
        x, wv, v_ws, nullptr, 4096, 1024, 4096, nullptr, nullptr, NKV_H);
    attn_kernel<<<dim3(8, 32, 2), 512, 0, stream>>>(q_ws, k_ws, v_ws, ctx_ws);
    gemm_kernel<0, true, false><<<dim3(32, 32), 256, 0, stream>>>(
        ctx_ws, wo, out, nullptr, 4096, 4096, 4096, nullptr, nullptr, 0);
  }
}

// Round 11
// 525.339 us; speedup vs baseline: 1.2722x; 1.0223x over previous
//
#include <hip/hip_runtime.h>
#include <math.h>

typedef short s16x8 __attribute__((ext_vector_type(8)));
typedef float f32x4 __attribute__((ext_vector_type(4)));
typedef unsigned u32x4 __attribute__((ext_vector_type(4)));
typedef unsigned short u16;

#define S_LEN 2048
#define HID_DIM 4096
#define NH_Q 32
#define NKV_H 8
#define DHEAD 128

__device__ __forceinline__ u16 f2bf(float f) {
  unsigned u = __builtin_bit_cast(unsigned, f);
  u += 0x7fffu + ((u >> 16) & 1u);
  return (u16)(u >> 16);
}

// async global -> LDS, 16B per lane; lds base wave-uniform, lane*16 auto-offset
__device__ __forceinline__ void gload16(const u16* g, u16* l) {
  __builtin_amdgcn_global_load_lds(
      (const __attribute__((address_space(1))) void*)g,
      (__attribute__((address_space(3))) void*)l, 16, 0, 0);
}

// ---------------- f32 -> bf16 bulk convert (single region) ----------------
__global__ void cvt_kernel(const float* __restrict__ in, u16* __restrict__ out, int n4) {
  int stride = gridDim.x * blockDim.x;
  for (int i = blockIdx.x * blockDim.x + threadIdx.x; i < n4; i += stride) {
    float4 f = ((const float4*)in)[i];
    uint2 o;
    o.x = (unsigned)f2bf(f.x) | ((unsigned)f2bf(f.y) << 16);
    o.y = (unsigned)f2bf(f.z) | ((unsigned)f2bf(f.w) << 16);
    ((uint2*)out)[i] = o;
  }
}

// ---- fused: x|wq|wk|wv[|wo] f32->bf16 + RoPE tables, one launch ----
__global__ void cvt_all_kernel(const float* __restrict__ x, const float* __restrict__ wq,
                               const float* __restrict__ wk, const float* __restrict__ wv,
                               const float* __restrict__ wo, u16* __restrict__ x_bf,
                               u16* __restrict__ wqkv_bf, u16* __restrict__ wo_bf,
                               const int* __restrict__ positions, float* __restrict__ cos_t,
                               float* __restrict__ sin_t, int with_wo) {
  const int R0 = 4194304, R1 = 8388608, R2 = 9437184, R3 = 10485760, R4 = 14680064;
  const int cvt_end = with_wo ? R4 : R3;
  const int rope_units = 32768;  // 2048*64 / 4
  const int total = cvt_end + rope_units;
  const int stride = gridDim.x * blockDim.x;
  for (int i = blockIdx.x * blockDim.x + threadIdx.x; i < total; i += stride) {
    if (i < cvt_end) {
      const float* src;
      u16* dst;
      int off;
      if (i < R0)      { src = x;  dst = x_bf;               off = i; }
      else if (i < R1) { src = wq; dst = wqkv_bf;            off = i - R0; }
      else if (i < R2) { src = wk; dst = wqkv_bf + 16777216; off = i - R1; }
      else if (i < R3) { src = wv; dst = wqkv_bf + 20971520; off = i - R2; }
      else             { src = wo; dst = wo_bf;              off = i - R3; }
      float4 f = ((const float4*)src)[off];
      uint2 o;
      o.x = (unsigned)f2bf(f.x) | ((unsigned)f2bf(f.y) << 16);
      o.y = (unsigned)f2bf(f.z) | ((unsigned)f2bf(f.w) << 16);
      ((uint2*)dst)[off] = o;
    } else {
      int base = (i - cvt_end) * 4;
#pragma unroll
      for (int e = 0; e < 4; ++e) {
        int idx = base + e;
        int s = idx >> 6, j = idx & 63;
        float pos = (float)positions[s];
        float inv = expf(-(float)j * (9.210340371976184f / 64.0f));
        float sv, cv;
        sincosf(pos * inv, &sv, &cv);
        cos_t[idx] = cv;
        sin_t[idx] = sv;
      }
    }
  }
}

// ---------------- RoPE tables (fallback path) ----------------
__global__ void rope_table_kernel(const int* __restrict__ positions,
                                  float* __restrict__ cos_t, float* __restrict__ sin_t) {
  int idx = blockIdx.x * 256 + threadIdx.x;
  if (idx >= S_LEN * 64) return;
  int s = idx >> 6, j = idx & 63;
  float pos = (float)positions[s];
  float inv = expf(-(float)j * (9.210340371976184f / 64.0f));
  float sv, cv;
  sincosf(pos * inv, &sv, &cv);
  cos_t[idx] = cv;
  sin_t[idx] = sv;
}

// ---------------- QKV GEMM: 128x256 tile, 2-phase, triple-buffer ----------------
// C = A[M][K]*B[N][K]^T, fused QKV epilogue. BK=64, 8 waves (2M x 4N), 144KB LDS
// (3 buf: A 16KB + B 32KB each), exact-round grid (768 = 3 x 256 CUs).
// Per K-tile: P1 {readA 8 + readB h0 4; stage A(t+2) + B h0(t+2) = 4 gloads},
// P2 {readB h1 4; stage B h1(t+2) = 2; vmcnt(6) = drain tile t+1, keep t+2}.
// Wave (wr,wc): rows wr*64 + mf*16 (mf 0..3); cols wc*16 + (nfi&1)*64 +
// (nfi>>1)*128 -> RoPE pairs (j, j+64) in-wave. Swizzle: slot phys = log ^ (row&7).
__global__ __launch_bounds__(512, 2) void gemmq_kernel(
    const u16* __restrict__ A, const u16* __restrict__ B,
    void* __restrict__ outp, int M, int N, int K,
    const float* __restrict__ cos_t, const float* __restrict__ sin_t) {
  __shared__ u16 LDS[73728];  // 144 KB: A 3x8192 elems, B 3x16384 at 24576
  const int t = threadIdx.x;
  const int wave = t >> 6, lane = t & 63;
  const int l15 = lane & 15, lhi = lane >> 4;
  const int wr = wave >> 2, wc = wave & 3;
  const int gx = gridDim.x;
  const int nwg = gx * gridDim.y;
  const int id = blockIdx.y * gx + blockIdx.x;
  const int swz = (id & 7) * (nwg >> 3) + (id >> 3);
  const int bm = (swz / gx) * 128, bn = (swz % gx) * 256;

  // read-side fragment offsets (slot ^ (l15&7); conflict-free, proven R8-R10)
  const int sw = l15 & 7;
  int aoff[4][2], boff[2][2];
#pragma unroll
  for (int q = 0; q < 4; ++q)
#pragma unroll
    for (int ks = 0; ks < 2; ++ks)
      aoff[q][ks] = wr * 4096 + (q * 16 + l15) * 64 + (((ks << 2) + lhi) ^ sw) * 8;
#pragma unroll
  for (int f = 0; f < 2; ++f)
#pragma unroll
    for (int ks = 0; ks < 2; ++ks)
      boff[f][ks] = (f * 64 + wc * 16 + l15) * 64 + (((ks << 2) + lhi) ^ sw) * 8;

  // staging: thread t covers slot t of an 8KB half (row t>>3, 16B slot t&7)
  const int lr1 = t >> 3;                     // 0..63
  const int cs1 = ((t & 7) ^ (lr1 & 7)) * 8;  // inverse swizzle
  const int ldsw = wave * 512;

  const f32x4 fz = {0.f, 0.f, 0.f, 0.f};
  f32x4 acc[4][4];
#pragma unroll
  for (int mf = 0; mf < 4; ++mf)
#pragma unroll
    for (int nf = 0; nf < 4; ++nf) acc[mf][nf] = fz;

  auto stageA = [&](int tile, int buf) {  // both halves: 2 gloads
    const size_t kb = (size_t)tile * 64;
    gload16(A + (size_t)(bm + lr1) * K + kb + cs1, &LDS[buf * 8192 + ldsw]);
    gload16(A + (size_t)(bm + 64 + lr1) * K + kb + cs1, &LDS[buf * 8192 + 4096 + ldsw]);
  };
  auto stageB = [&](int tile, int h, int buf) {  // one half: 2 gloads
    const size_t kb = (size_t)tile * 64;
    gload16(B + (size_t)(bn + h * 128 + lr1) * K + kb + cs1,
            &LDS[24576 + buf * 16384 + h * 8192 + ldsw]);
    gload16(B + (size_t)(bn + h * 128 + 64 + lr1) * K + kb + cs1,
            &LDS[24576 + buf * 16384 + h * 8192 + 4096 + ldsw]);
  };

  s16x8 afr[4][2], bfr[2][2];
  auto readA = [&](int buf) {  // this wave's A rows live in half wr
    const int base = buf * 8192;
#pragma unroll
    for (int q = 0; q < 4; ++q)
#pragma unroll
      for (int ks = 0; ks < 2; ++ks)
        afr[q][ks] = *(const s16x8*)&LDS[base + aoff[q][ks]];
  };
  auto readB = [&](int nfH, int buf) {
    const int base = 24576 + buf * 16384 + nfH * 8192;
#pragma unroll
    for (int f = 0; f < 2; ++f)
#pragma unroll
      for (int ks = 0; ks < 2; ++ks)
        bfr[f][ks] = *(const s16x8*)&LDS[base + boff[f][ks]];
  };
  auto mfma16 = [&](int nfH) {
    __builtin_amdgcn_s_setprio(1);
#pragma unroll
    for (int q = 0; q < 4; ++q)
#pragma unroll
      for (int f = 0; f < 2; ++f)
#pragma unroll
        for (int ks = 0; ks < 2; ++ks)
          acc[q][nfH * 2 + f] = __builtin_amdgcn_mfma_f32_16x16x32_bf16(
              afr[q][ks], bfr[f][ks], acc[q][nfH * 2 + f], 0, 0, 0);
    __builtin_amdgcn_s_setprio(0);
  };

#define PHASE_SYNC()                        \
  do {                                      \
    __builtin_amdgcn_s_barrier();           \
    asm volatile("s_waitcnt lgkmcnt(0)");   \
    __builtin_amdgcn_sched_barrier(0);      \
  } while (0)

  // prologue: stage tiles 0,1 fully (6 loads each); wait tile0 (t1's 6 in flight)
  stageA(0, 0); stageB(0, 0, 0); stageB(0, 1, 0);
  stageA(1, 1); stageB(1, 0, 1); stageB(1, 1, 1);
  asm volatile("s_waitcnt vmcnt(6)");
  __builtin_amdgcn_sched_barrier(0);
  __builtin_amdgcn_s_barrier();

  const int nt = K >> 6;
  int cur = 0, nx2 = 2;
  for (int tt = 0; tt < nt; ++tt) {
    const bool s2 = (tt + 2) < nt;
    // P1: reads A (8) + B half0 (4); stage tile t+2: A both halves + B half0 (4 loads)
    readA(cur); readB(0, cur);
    if (s2) { stageA(tt + 2, nx2); stageB(tt + 2, 0, nx2); }
    PHASE_SYNC(); mfma16(0); __builtin_amdgcn_s_barrier();
    // P2: reads B half1 (4); stage B half1(t+2) (2 loads); counted wait
    readB(1, cur);
    if (s2) { stageB(tt + 2, 1, nx2); asm volatile("s_waitcnt vmcnt(6)"); }
    else    { asm volatile("s_waitcnt vmcnt(0)"); }
    PHASE_SYNC(); mfma16(1); __builtin_amdgcn_s_barrier();
    cur = (cur == 2) ? 0 : cur + 1;
    nx2 = (nx2 == 2) ? 0 : nx2 + 1;
  }
#undef PHASE_SYNC

  // ---- fused QKV epilogue: row = bm + wr*64 + mf*16 + lhi*4 + i;
  //      col = bn + wc*16 + (nfi&1)*64 + (nfi>>1)*128 + l15
  u16* qp = (u16*)outp;
  u16* kp = qp + 16777216;  // 2*32*2048*128
  u16* vp = kp + 4194304;   // 2*8*2048*128
  if (bn < 5120) {
    const bool isQ = bn < 4096;
    u16* O = isQ ? qp : kp;
    const int hb = isQ ? (bn >> 7) : ((bn - 4096) >> 7);
    const int Hh = isQ ? NH_Q : NKV_H;
    const int j = wc * 16 + l15;  // 0..63
#pragma unroll
    for (int mf = 0; mf < 4; ++mf) {
      int rb = bm + wr * 64 + mf * 16 + lhi * 4;
#pragma unroll
      for (int p = 0; p < 2; ++p) {
        int head = hb + p;
#pragma unroll
        for (int i = 0; i < 4; ++i) {
          int m = rb + i;
          int b = m >> 11, srw = m & 2047;
          float c = cos_t[srw * 64 + j];
          float s = sin_t[srw * 64 + j];
          float x0 = acc[mf][2 * p][i];
          float x1 = acc[mf][2 * p + 1][i];
          size_t base = ((size_t)(b * Hh + head) * S_LEN + srw) * DHEAD;
          O[base + j] = f2bf(x0 * c - x1 * s);
          O[base + j + 64] = f2bf(x0 * s + x1 * c);
        }
      }
    }
  } else {  // V transposed [b][h][d][s]
#pragma unroll
    for (int mf = 0; mf < 4; ++mf) {
      int rb = bm + wr * 64 + mf * 16 + lhi * 4;
#pragma unroll
      for (int nfi = 0; nfi < 4; ++nfi) {
        int colrel = bn - 5120 + wc * 16 + (nfi & 1) * 64 + (nfi >> 1) * 128 + l15;
        int head = colrel >> 7, d = colrel & 127;
#pragma unroll
        for (int i = 0; i < 4; ++i) {
          int m = rb + i;
          int b = m >> 11, srw = m & 2047;
          vp[((size_t)(b * NKV_H + head) * DHEAD + d) * S_LEN + srw] = f2bf(acc[mf][nfi][i]);
        }
      }
    }
  }
}

// ---------------- 8-phase 256^2 GEMM (R10, out-proj): C = A*B^T, f32 out ----
__global__ __launch_bounds__(512, 2) void gemm8ph_kernel(
    const u16* __restrict__ A, const u16* __restrict__ B,
    void* __restrict__ outp, int M, int N, int K) {
  __shared__ u16 LDS[65536];
  const int t = threadIdx.x;
  const int wave = t >> 6, lane = t & 63;
  const int l15 = lane & 15, lhi = lane >> 4;
  const int wr = wave >> 2, wc = wave & 3;
  const int gx = gridDim.x;
  const int nwg = gx * gridDim.y;
  const int id = blockIdx.y * gx + blockIdx.x;
  const int swz = (id & 7) * (nwg >> 3) + (id >> 3);
  const int bm = (swz / gx) * 256, bn = (swz % gx) * 256;

  const int sw = l15 & 7;
  int aoff[4][2], boff[2][2];
#pragma unroll
  for (int q = 0; q < 4; ++q)
#pragma unroll
    for (int ks = 0; ks < 2; ++ks)
      aoff[q][ks] = (wr * 64 + q * 16 + l15) * 64 + (((ks << 2) + lhi) ^ sw) * 8;
#pragma unroll
  for (int f = 0; f < 2; ++f)
#pragma unroll
    for (int ks = 0; ks < 2; ++ks)
      boff[f][ks] = (f * 64 + wc * 16 + l15) * 64 + (((ks << 2) + lhi) ^ sw) * 8;

  const int lr1 = t >> 3;
  const int cs1 = ((t & 7) ^ (lr1 & 7)) * 8;
  const int rA1 = lr1;
  const int rA2 = 128 + lr1;
  const int ldsw = wave * 512;

  const f32x4 fz = {0.f, 0.f, 0.f, 0.f};
  f32x4 acc[8][4];
#pragma unroll
  for (int mf = 0; mf < 8; ++mf)
#pragma unroll
    for (int nf = 0; nf < 4; ++nf) acc[mf][nf] = fz;

  auto stageA = [&](int tile, int h, int buf) {
    const size_t kb = (size_t)tile * 64;
    gload16(A + (size_t)(bm + h * 64 + rA1) * K + kb + cs1,
            &LDS[buf * 16384 + h * 8192 + ldsw]);
    gload16(A + (size_t)(bm + h * 64 + rA2) * K + kb + cs1,
            &LDS[buf * 16384 + h * 8192 + 4096 + ldsw]);
  };
  auto stageB = [&](int tile, int h, int buf) {
    const size_t kb = (size_t)tile * 64;
    gload16(B + (size_t)(bn + h * 128 + lr1) * K + kb + cs1,
            &LDS[32768 + buf * 16384 + h * 8192 + ldsw]);
    gload16(B + (size_t)(bn + h * 128 + 64 + lr1) * K + kb + cs1,
            &LDS[32768 + buf * 16384 + h * 8192 + 4096 + ldsw]);
  };

  s16x8 afr[4][2], bfr[2][2], bfrK[2][2];
  auto readA = [&](int mfH, int buf) {
    const int base = buf * 16384 + mfH * 8192;
#pragma unroll
    for (int q = 0; q < 4; ++q)
#pragma unroll
      for (int ks = 0; ks < 2; ++ks)
        afr[q][ks] = *(const s16x8*)&LDS[base + aoff[q][ks]];
  };
  auto readB = [&](int nfH, int buf, s16x8 (&dst)[2][2]) {
    const int base = 32768 + buf * 16384 + nfH * 8192;
#pragma unroll
    for (int f = 0; f < 2; ++f)
#pragma unroll
      for (int ks = 0; ks < 2; ++ks)
        dst[f][ks] = *(const s16x8*)&LDS[base + boff[f][ks]];
  };
  auto mfma16 = [&](int mfH, int nfH, const s16x8 (&bb)[2][2]) {
    __builtin_amdgcn_s_setprio(1);
#pragma unroll
    for (int q = 0; q < 4; ++q)
#pragma unroll
      for (int f = 0; f < 2; ++f)
#pragma unroll
        for (int ks = 0; ks < 2; ++ks)
          acc[mfH * 4 + q][nfH * 2 + f] = __builtin_amdgcn_mfma_f32_16x16x32_bf16(
              afr[q][ks], bb[f][ks], acc[mfH * 4 + q][nfH * 2 + f], 0, 0, 0);
    __builtin_amdgcn_s_setprio(0);
  };

#define PHASE_SYNC()                        \
  do {                                      \
    __builtin_amdgcn_s_barrier();           \
    asm volatile("s_waitcnt lgkmcnt(0)");   \
    __builtin_amdgcn_sched_barrier(0);      \
  } while (0)

  stageA(0, 0, 0); stageB(0, 0, 0); stageB(0, 1, 0); stageA(0, 1, 0);
  stageA(1, 0, 1); stageB(1, 0, 1); stageB(1, 1, 1);
  asm volatile("s_waitcnt vmcnt(6)");
  __builtin_amdgcn_sched_barrier(0);
  __builtin_amdgcn_s_barrier();

  const int nt = K >> 6;
  for (int i = 0; i < (nt >> 1); ++i) {
    const int u = 2 * i, v = 2 * i + 1;
    const bool s2 = (u + 2) < nt;
    readA(0, 0); readB(0, 0, bfrK); stageA(v, 1, 1);
    PHASE_SYNC(); mfma16(0, 0, bfrK); __builtin_amdgcn_s_barrier();
    readB(1, 0, bfr); if (s2) stageB(u + 2, 0, 0);
    PHASE_SYNC(); mfma16(0, 1, bfr); __builtin_amdgcn_s_barrier();
    readA(1, 0); if (s2) stageB(u + 2, 1, 0);
    PHASE_SYNC(); mfma16(1, 1, bfr); __builtin_amdgcn_s_barrier();
    if (s2) { stageA(u + 2, 0, 0); asm volatile("s_waitcnt vmcnt(6)"); }
    else    { asm volatile("s_waitcnt vmcnt(0)"); }
    PHASE_SYNC(); mfma16(1, 0, bfrK); __builtin_amdgcn_s_barrier();
    readA(0, 1); readB(0, 1, bfrK); if (s2) stageA(u + 2, 1, 0);
    PHASE_SYNC(); mfma16(0, 0, bfrK); __builtin_amdgcn_s_barrier();
    readB(1, 1, bfr); if (s2) stageB(v + 2, 0, 1);
    PHASE_SYNC(); mfma16(0, 1, bfr); __builtin_amdgcn_s_barrier();
    readA(1, 1); if (s2) stageB(v + 2, 1, 1);
    PHASE_SYNC(); mfma16(1, 1, bfr); __builtin_amdgcn_s_barrier();
    if (s2) { stageA(v + 2, 0, 1); asm volatile("s_waitcnt vmcnt(6)"); }
    else    { asm volatile("s_waitcnt vmcnt(0)"); }
    PHASE_SYNC(); mfma16(1, 0, bfrK); __builtin_amdgcn_s_barrier();
  }
#undef PHASE_SYNC

  float* C = (float*)outp;
#pragma unroll
  for (int mf = 0; mf < 8; ++mf) {
    int rb = bm + wr * 128 + mf * 16 + lhi * 4;
#pragma unroll
    for (int nfi = 0; nfi < 4; ++nfi) {
      int col = bn + wc * 16 + (nfi & 1) * 64 + (nfi >> 1) * 128 + l15;
#pragma unroll
      for (int i = 0; i < 4; ++i) C[(size_t)(rb + i) * N + col] = acc[mf][nfi][i];
    }
  }
}

// ---------------- reg-staged GEMM (fallback path only) ----------------
template<int EPI, bool ABF16, bool BBF16>
__global__ __launch_bounds__(256) void gemm_kernel(
    const void* __restrict__ Aptr, const void* __restrict__ Bptr,
    void* __restrict__ outp, void* __restrict__ outp2, int M, int N, int K,
    const float* __restrict__ cos_t, const float* __restrict__ sin_t, int Hh) {
  __shared__ u16 As[128][72];
  __shared__ u16 Bs[128][72];
  const int t = threadIdx.x;
  const int wave = t >> 6, lane = t & 63;
  const int l15 = lane & 15, lhi = lane >> 4;
  const int gx = gridDim.x;
  const int nwg = gx * gridDim.y;
  const int id = blockIdx.y * gx + blockIdx.x;
  const int swz = (id & 7) * (nwg >> 3) + (id >> 3);
  const int bm = (swz / gx) * 128, bn = (swz % gx) * 128;

  const f32x4 fz = {0.f, 0.f, 0.f, 0.f};
  f32x4 acc[2][8];
#pragma unroll
  for (int a0 = 0; a0 < 2; ++a0)
#pragma unroll
    for (int b0 = 0; b0 < 8; ++b0) acc[a0][b0] = fz;

  for (int kt = 0; kt < K; kt += 64) {
    __syncthreads();
    if (ABF16) {
      const u16* A = (const u16*)Aptr;
#pragma unroll
      for (int p = 0; p < 4; ++p) {
        int row = p * 32 + (t >> 3), kc = (t & 7) * 8;
        *(s16x8*)&As[row][kc] = *(const s16x8*)(A + (size_t)(bm + row) * K + kt + kc);
      }
    } else {
      const float* A = (const float*)Aptr;
#pragma unroll
      for (int p = 0; p < 8; ++p) {
        int row = p * 16 + (t >> 4), kc = (t & 15) * 4;
        float4 f = *(const float4*)(A + (size_t)(bm + row) * K + kt + kc);
        unsigned* dst = (unsigned*)&As[row][kc];
        dst[0] = (unsigned)f2bf(f.x) | ((unsigned)f2bf(f.y) << 16);
        dst[1] = (unsigned)f2bf(f.z) | ((unsigned)f2bf(f.w) << 16);
      }
    }
    if (BBF16) {
      const u16* Bw = (const u16*)Bptr;
#pragma unroll
      for (int p = 0; p < 4; ++p) {
        int row = p * 32 + (t >> 3), kc = (t & 7) * 8;
        *(s16x8*)&Bs[row][kc] = *(const s16x8*)(Bw + (size_t)(bn + row) * K + kt + kc);
      }
    } else {
      const float* Bw = (const float*)Bptr;
#pragma unroll
      for (int p = 0; p < 8; ++p) {
        int row = p * 16 + (t >> 4), kc = (t & 15) * 4;
        float4 f = *(const float4*)(Bw + (size_t)(bn + row) * K + kt + kc);
        unsigned* dst = (unsigned*)&Bs[row][kc];
        dst[0] = (unsigned)f2bf(f.x) | ((unsigned)f2bf(f.y) << 16);
        dst[1] = (unsigned)f2bf(f.z) | ((unsigned)f2bf(f.w) << 16);
      }
    }
    __syncthreads();
#pragma unroll
    for (int ks = 0; ks < 2; ++ks) {
      s16x8 bfr[8];
#pragma unroll
      for (int nf = 0; nf < 8; ++nf)
        bfr[nf] = *(const s16x8*)&Bs[nf * 16 + l15][ks * 32 + lhi * 8];
#pragma unroll
      for (int mf = 0; mf < 2; ++mf) {
        s16x8 a = *(const s16x8*)&As[wave * 32 + mf * 16 + l15][ks * 32 + lhi * 8];
#pragma unroll
        for (int nf = 0; nf < 8; ++nf)
          acc[mf][nf] = __builtin_amdgcn_mfma_f32_16x16x32_bf16(a, bfr[nf], acc[mf][nf], 0, 0, 0);
      }
    }
  }

  if (EPI == 0) {
    float* C = (float*)outp;
#pragma unroll
    for (int mf = 0; mf < 2; ++mf)
#pragma unroll
      for (int nf = 0; nf < 8; ++nf) {
        int col = bn + nf * 16 + l15;
        int rb = bm + wave * 32 + mf * 16 + lhi * 4;
#pragma unroll
        for (int i = 0; i < 4; ++i) C[(size_t)(rb + i) * N + col] = acc[mf][nf][i];
      }
  } else if (EPI == 2) {
    u16* O = (u16*)outp;
    int h = bn >> 7;
#pragma unroll
    for (int mf = 0; mf < 2; ++mf)
#pragma unroll
      for (int nf = 0; nf < 4; ++nf) {
        int j = nf * 16 + l15;
        int rb = bm + wave * 32 + mf * 16 + lhi * 4;
#pragma unroll
        for (int i = 0; i < 4; ++i) {
          int m = rb + i;
          int b = m >> 11, srow = m & 2047;
          float c = cos_t[srow * 64 + j];
          float s = sin_t[srow * 64 + j];
          float x0 = acc[mf][nf][i];
          float x1 = acc[mf][nf + 4][i];
          size_t base = ((size_t)(b * Hh + h) * S_LEN + srow) * DHEAD;
          O[base + j] = f2bf(x0 * c - x1 * s);
          O[base + j + 64] = f2bf(x0 * s + x1 * c);
        }
      }
  } else {  // EPI == 4: bf16 transposed [b][h][d][s]
    u16* O = (u16*)outp;
#pragma unroll
    for (int mf = 0; mf < 2; ++mf)
#pragma unroll
      for (int nf = 0; nf < 8; ++nf) {
        int col = bn + nf * 16 + l15;
        int h = col >> 7, d = col & 127;
        int rb = bm + wave * 32 + mf * 16 + lhi * 4;
#pragma unroll
        for (int i = 0; i < 4; ++i) {
          int m = rb + i;
          int b = m >> 11, srow = m & 2047;
          O[((size_t)(b * Hh + h) * DHEAD + d) * S_LEN + srow] = f2bf(acc[mf][nf][i]);
        }
      }
  }
}

// ---------------- Flash attention (causal, GQA) ----------------
#define KIDX(r, c) (((r) * 128 + (c)) ^ (((r) & 7) << 3))
#define VIDX(d, kv) (((d) * 64 + (kv)) ^ (((d) & 7) << 3))
__global__ __launch_bounds__(512) void attn_kernel(
    const u16* __restrict__ q, const u16* __restrict__ k, const u16* __restrict__ vt,
    u16* __restrict__ ctx) {
  __shared__ u16 Ks[64 * 128];
  __shared__ u16 Vts[128 * 64];

  const int t = threadIdx.x;
  const int wave = t >> 6, lane = t & 63;
  const int l15 = lane & 15, lhi = lane >> 4;
  const int pi = blockIdx.x, h = blockIdx.y, b = blockIdx.z;
  const int kvh = h >> 2;
  const int qsub[2] = {pi, 15 - pi};
  const int ntiles = 32 - 2 * pi;

  const u16* qb = q + ((size_t)(b * NH_Q + h)) * S_LEN * DHEAD;
  const u16* kb = k + ((size_t)(b * NKV_H + kvh)) * S_LEN * DHEAD;
  const u16* vtb = vt + ((size_t)(b * NKV_H + kvh)) * DHEAD * S_LEN;

  s16x8 qf[2][4];
#pragma unroll
  for (int s = 0; s < 2; ++s)
#pragma unroll
    for (int ks = 0; ks < 4; ++ks)
      qf[s][ks] = *(const s16x8*)(qb + (size_t)(qsub[s] * 128 + wave * 16 + l15) * DHEAD +
                                  ks * 32 + lhi * 8);

  const f32x4 fz = {0.f, 0.f, 0.f, 0.f};
  f32x4 acc[2][8];
#pragma unroll
  for (int s = 0; s < 2; ++s)
#pragma unroll
    for (int i = 0; i < 8; ++i) acc[s][i] = fz;
  float mrow[2] = {-INFINITY, -INFINITY};
  float lsum[2] = {0.f, 0.f};

  const float scale = 0.08838834764831845f;

  const int sl0 = l15 | (((2 * lhi) & 3) << 4);
  const int sl1 = sl0 | 16;
  const bool hisel = (lhi & 2) != 0;

  const int krow = t >> 3, kd0 = (t & 7) * 16;
  const int vrow = t >> 2, vk0 = (t & 3) * 16;
  s16x8 kr0, kr1, vr0, vr1;
  {
    const u16* p = kb + (size_t)krow * DHEAD + kd0;
    kr0 = *(const s16x8*)p;
    kr1 = *(const s16x8*)(p + 8);
    const u16* pv = vtb + (size_t)vrow * S_LEN + vk0;
    vr0 = *(const s16x8*)pv;
    vr1 = *(const s16x8*)(pv + 8);
  }

  for (int tt = 0; tt < ntiles; ++tt) {
    __syncthreads();
    *(s16x8*)&Ks[KIDX(krow, kd0)] = kr0;
    *(s16x8*)&Ks[KIDX(krow, kd0 + 8)] = kr1;
    *(s16x8*)&Vts[VIDX(vrow, vk0)] = vr0;
    *(s16x8*)&Vts[VIDX(vrow, vk0 + 8)] = vr1;
    __syncthreads();
    if (tt + 1 < ntiles) {
      const u16* p = kb + (size_t)((tt + 1) * 64 + krow) * DHEAD + kd0;
      kr0 = *(const s16x8*)p;
      kr1 = *(const s16x8*)(p + 8);
      const u16* pv = vtb + (size_t)vrow * S_LEN + (tt + 1) * 64 + vk0;
      vr0 = *(const s16x8*)pv;
      vr1 = *(const s16x8*)(pv + 8);
    }

    const int kc_base = tt * 64;
#pragma unroll
    for (int s = 0; s < 2; ++s) {
      const int wmin = qsub[s] * 128 + wave * 16;
      if (kc_base > wmin + 15) continue;
      f32x4 sacc[4];
#pragma unroll
      for (int i = 0; i < 4; ++i) sacc[i] = fz;
      __builtin_amdgcn_s_setprio(1);
#pragma unroll
      for (int ks = 0; ks < 4; ++ks) {
#pragma unroll
        for (int nf = 0; nf < 4; ++nf) {
          s16x8 kf = *(const s16x8*)&Ks[KIDX(nf * 16 + l15, ks * 32 + lhi * 8)];
          sacc[nf] = __builtin_amdgcn_mfma_f32_16x16x32_bf16(kf, qf[s][ks], sacc[nf], 0, 0, 0);
        }
      }
      __builtin_amdgcn_s_setprio(0);

      const int qg = wmin + l15;
      float pmax = -INFINITY;
      if (kc_base + 63 > wmin) {
#pragma unroll
        for (int nf = 0; nf < 4; ++nf)
#pragma unroll
          for (int i = 0; i < 4; ++i) {
            int kv = kc_base + nf * 16 + lhi * 4 + i;
            float sv = sacc[nf][i] * scale;
            sv = (kv <= qg) ? sv : -INFINITY;
            sacc[nf][i] = sv;
            pmax = fmaxf(pmax, sv);
          }
      } else {
#pragma unroll
        for (int nf = 0; nf < 4; ++nf)
#pragma unroll
          for (int i = 0; i < 4; ++i) {
            float sv = sacc[nf][i] * scale;
            sacc[nf][i] = sv;
            pmax = fmaxf(pmax, sv);
          }
      }
      pmax = fmaxf(pmax, __shfl_xor(pmax, 16, 64));
      pmax = fmaxf(pmax, __shfl_xor(pmax, 32, 64));

      if (!__all(pmax <= mrow[s] + 8.0f)) {
        float mnew = fmaxf(mrow[s], pmax);
        float alpha = __expf(mrow[s] - mnew);
        mrow[s] = mnew;
        lsum[s] *= alpha;
#pragma unroll
        for (int i = 0; i < 4; ++i) {
          float al = __shfl(alpha, (lane & 48) | (lhi * 4 + i), 64);
#pragma unroll
          for (int df = 0; df < 8; ++df) acc[s][df][i] *= al;
        }
      }

      float rsum = 0.f;
      unsigned pk[4][2];
#pragma unroll
      for (int nf = 0; nf < 4; ++nf) {
        float p0 = __expf(sacc[nf][0] - mrow[s]);
        float p1 = __expf(sacc[nf][1] - mrow[s]);
        float p2 = __expf(sacc[nf][2] - mrow[s]);
        float p3 = __expf(sacc[nf][3] - mrow[s]);
        rsum += (p0 + p1) + (p2 + p3);
        pk[nf][0] = (unsigned)f2bf(p0) | ((unsigned)f2bf(p1) << 16);
        pk[nf][1] = (unsigned)f2bf(p2) | ((unsigned)f2bf(p3) << 16);
      }
      rsum += __shfl_xor(rsum, 16, 64);
      rsum += __shfl_xor(rsum, 32, 64);
      lsum[s] += rsum;

      s16x8 pa[2];
#pragma unroll
      for (int ph = 0; ph < 2; ++ph) {
        unsigned lo0 = __shfl((int)pk[2 * ph][0], sl0, 64);
        unsigned hi0 = __shfl((int)pk[2 * ph + 1][0], sl0, 64);
        unsigned lo1 = __shfl((int)pk[2 * ph][1], sl0, 64);
        unsigned hi1 = __shfl((int)pk[2 * ph + 1][1], sl0, 64);
        unsigned lo2 = __shfl((int)pk[2 * ph][0], sl1, 64);
        unsigned hi2 = __shfl((int)pk[2 * ph + 1][0], sl1, 64);
        unsigned lo3 = __shfl((int)pk[2 * ph][1], sl1, 64);
        unsigned hi3 = __shfl((int)pk[2 * ph + 1][1], sl1, 64);
        u32x4 w;
        w[0] = hisel ? hi0 : lo0;
        w[1] = hisel ? hi1 : lo1;
        w[2] = hisel ? hi2 : lo2;
        w[3] = hisel ? hi3 : lo3;
        pa[ph] = __builtin_bit_cast(s16x8, w);
      }

      __builtin_amdgcn_s_setprio(1);
#pragma unroll
      for (int ph = 0; ph < 2; ++ph) {
#pragma unroll
        for (int df = 0; df < 8; ++df) {
          s16x8 bb = *(const s16x8*)&Vts[VIDX(df * 16 + l15, ph * 32 + lhi * 8)];
          acc[s][df] = __builtin_amdgcn_mfma_f32_16x16x32_bf16(pa[ph], bb, acc[s][df], 0, 0, 0);
        }
      }
      __builtin_amdgcn_s_setprio(0);
    }
  }

#pragma unroll
  for (int s = 0; s < 2; ++s) {
    float rl = 1.0f / lsum[s];
#pragma unroll
    for (int i = 0; i < 4; ++i) {
      float rli = __shfl(rl, (lane & 48) | (lhi * 4 + i), 64);
      int m = b * S_LEN + qsub[s] * 128 + wave * 16 + lhi * 4 + i;
#pragma unroll
      for (int df = 0; df < 8; ++df) {
        int col = h * DHEAD + df * 16 + l15;
        ctx[(size_t)m * (NH_Q * DHEAD) + col] = f2bf(acc[s][df][i] * rli);
      }
    }
  }
}

extern "C" void kernel_launch(void* const* d_in, const int* in_sizes, int n_in,
                              void* d_out, int out_size, void* d_ws, size_t ws_size,
                              hipStream_t stream) {
  const float* x = (const float*)d_in[0];
  const int* positions = (const int*)d_in[1];
  const float* wq = (const float*)d_in[2];
  const float* wk = (const float*)d_in[3];
  const float* wv = (const float*)d_in[4];
  const float* wo = (const float*)d_in[5];
  float* out = (float*)d_out;

  char* ws = (char*)d_ws;
  const size_t MB1 = 1048576;
  const size_t SZ_X = 33554432;     // 2*2048*4096 bf16
  const size_t SZ_WQKV = 50331648;  // 6144*4096 bf16
  const size_t SZ_WO = 33554432;    // 4096*4096 bf16
  const size_t SZ_Q = 33554432;     // q bf16
  const size_t SZ_WK = 8388608;     // k or v bf16
  const size_t NEED_FULL = MB1 + SZ_X + SZ_WQKV + SZ_Q + 2 * SZ_WK;  // 129 MB
  const size_t NEED_WO = NEED_FULL + SZ_WO;                          // 161 MB

  float* cos_t = (float*)ws;
  float* sin_t = (float*)(ws + MB1 / 2);

  if (ws_size >= NEED_WO) {
    char* p = ws + MB1;
    u16* x_bf = (u16*)p;    p += SZ_X;     // later reused as ctx
    u16* wqkv_bf = (u16*)p; p += SZ_WQKV;  // wq|wk|wv stacked
    u16* wo_bf = (u16*)p;   p += SZ_WO;
    u16* q_ws = (u16*)p;    p += SZ_Q;     // q | k | v contiguous
    u16* k_ws = (u16*)p;    p += SZ_WK;
    u16* v_ws = (u16*)p;    p += SZ_WK;
    u16* ctx_ws = x_bf;

    cvt_all_kernel<<<2048, 256, 0, stream>>>(x, wq, wk, wv, wo, x_bf, wqkv_bf, wo_bf,
                                             positions, cos_t, sin_t, 1);
    // fused QKV: 128x256 tiles, grid (24,32) = 768 blocks = 3 exact rounds
    gemmq_kernel<<<dim3(24, 32), 512, 0, stream>>>(
        x_bf, wqkv_bf, q_ws, 4096, 6144, 4096, cos_t, sin_t);
    attn_kernel<<<dim3(8, 32, 2), 512, 0, stream>>>(q_ws, k_ws, v_ws, ctx_ws);
    gemm8ph_kernel<<<dim3(16, 16), 512, 0, stream>>>(
        ctx_ws, wo_bf, out, 4096, 4096, 4096);
  } else if (ws_size >= NEED_FULL) {
    char* p = ws + MB1;
    u16* x_bf = (u16*)p;    p += SZ_X;
    u16* wqkv_bf = (u16*)p; p += SZ_WQKV;
    u16* q_ws = (u16*)p;    p += SZ_Q;
    u16* k_ws = (u16*)p;    p += SZ_WK;
    u16* v_ws = (u16*)p;    p += SZ_WK;
    u16* ctx_ws = x_bf;

    cvt_all_kernel<<<2048, 256, 0, stream>>>(x, wq, wk, wv, nullptr, x_bf, wqkv_bf, nullptr,
                                             positions, cos_t, sin_t, 0);
    gemmq_kernel<<<dim3(24, 32), 512, 0, stream>>>(
        x_bf, wqkv_bf, q_ws, 4096, 6144, 4096, cos_t, sin_t);
    cvt_kernel<<<2048, 256, 0, stream>>>(wo, wqkv_bf, 4194304);  // wqkv_bf now = wo_bf
    attn_kernel<<<dim3(8, 32, 2), 512, 0, stream>>>(q_ws, k_ws, v_ws, ctx_ws);
    gemm8ph_kernel<<<dim3(16, 16), 512, 0, stream>>>(
        ctx_ws, wqkv_bf, out, 4096, 4096, 4096);
  } else {
    u16* q_ws = (u16*)(ws + MB1);
    u16* k_ws = (u16*)(ws + MB1 + SZ_Q);
    u16* v_ws = (u16*)(ws + MB1 + SZ_Q + SZ_WK);
    u16* ctx_ws = (u16*)(ws + MB1 + SZ_Q + 2 * SZ_WK);

    rope_table_kernel<<<512, 256, 0, stream>>>(positions, cos_t, sin_t);
    gemm_kernel<2, false, false><<<dim3(32, 32), 256, 0, stream>>>(
        x, wq, q_ws, nullptr, 4096, 4096, 4096, cos_t, sin_t, NH_Q);
    gemm_kernel<2, false, false><<<dim3(8, 32), 256, 0, stream>>>(
        x, wk, k_ws, nullptr, 4096, 1024, 4096, cos_t, sin_t, NKV_H);
    gemm_kernel<4, false, false><<<dim3(8, 32), 256, 0, stream>>>(
        x, wv, v_ws, nullptr, 4096, 1024, 4096, nullptr, nullptr, NKV_H);
    attn_kernel<<<dim3(8, 32, 2), 512, 0, stream>>>(q_ws, k_ws, v_ws, ctx_ws);
    gemm_kernel<0, true, false><<<dim3(32, 32), 256, 0, stream>>>(
        ctx_ws, wo, out, nullptr, 4096, 4096, 4096, nullptr, nullptr, 0);
  }
}